// Round 12
// baseline (218.662 us; speedup 1.0000x reference)
//
#include <hip/hip_runtime.h>
#include <hip/hip_fp16.h>

#define SLOPE_ATT 0.2f
#define SLOPE_ACT 0.01f

#define NB_CSR 128     // edge ranges in count/scatter passes
#define NXCD 8         // dst chunks == XCD count (blockIdx%8 -> XCD heuristic)

typedef _Float16 hf8 __attribute__((ext_vector_type(8)));
typedef float f32x4 __attribute__((ext_vector_type(4)));

// ---------------------------------------------------------------------------
// MFMA fp16 GEMM body: h[M][128] = A[M][K] @ B[K][128], BT[128][K] fp16.
// One wave = 32 rows x 128 cols. No LDS.
template<int K, int H, bool A_FP32>
__device__ __forceinline__
void gemm_mfma_body(int gbid, int tid,
                    const void* __restrict__ Av, const _Float16* __restrict__ BT,
                    const float* __restrict__ att_s, const float* __restrict__ att_d,
                    _Float16* __restrict__ hout, float* __restrict__ a_src,
                    float* __restrict__ a_dst, int M)
{
  const int lane = tid & 63;
  const int wid  = tid >> 6;
  const int li   = lane & 15;
  const int lk   = lane >> 4;
  const int rowbase = gbid * 128 + wid * 32;

  const float*    Af = (const float*)Av;
  const _Float16* Ah = (const _Float16*)Av;

  f32x4 acc[2][8];
#pragma unroll
  for (int i = 0; i < 2; ++i)
#pragma unroll
    for (int j = 0; j < 8; ++j) acc[i][j] = (f32x4){0.f, 0.f, 0.f, 0.f};

  const int r0 = min(rowbase + li,      M - 1);
  const int r1 = min(rowbase + 16 + li, M - 1);

#pragma unroll
  for (int ks = 0; ks < K / 32; ++ks) {
    const int kb = ks * 32 + lk * 8;
    hf8 a0, a1;
    if constexpr (A_FP32) {
      const float* p0 = &Af[(size_t)r0 * K + kb];
      const float* p1 = &Af[(size_t)r1 * K + kb];
      float4 x0a = *(const float4*)p0, x0b = *(const float4*)(p0 + 4);
      float4 x1a = *(const float4*)p1, x1b = *(const float4*)(p1 + 4);
      a0[0]=(_Float16)x0a.x; a0[1]=(_Float16)x0a.y; a0[2]=(_Float16)x0a.z; a0[3]=(_Float16)x0a.w;
      a0[4]=(_Float16)x0b.x; a0[5]=(_Float16)x0b.y; a0[6]=(_Float16)x0b.z; a0[7]=(_Float16)x0b.w;
      a1[0]=(_Float16)x1a.x; a1[1]=(_Float16)x1a.y; a1[2]=(_Float16)x1a.z; a1[3]=(_Float16)x1a.w;
      a1[4]=(_Float16)x1b.x; a1[5]=(_Float16)x1b.y; a1[6]=(_Float16)x1b.z; a1[7]=(_Float16)x1b.w;
    } else {
      a0 = *(const hf8*)&Ah[(size_t)r0 * K + kb];
      a1 = *(const hf8*)&Ah[(size_t)r1 * K + kb];
    }
#pragma unroll
    for (int cf = 0; cf < 8; ++cf) {
      hf8 b = *(const hf8*)&BT[(size_t)(cf * 16 + li) * K + kb];
      acc[0][cf] = __builtin_amdgcn_mfma_f32_16x16x32_f16(a0, b, acc[0][cf], 0, 0, 0);
      acc[1][cf] = __builtin_amdgcn_mfma_f32_16x16x32_f16(a1, b, acc[1][cf], 0, 0, 0);
    }
  }

  float sA[8], dA[8];
#pragma unroll
  for (int cf = 0; cf < 8; ++cf) {
    sA[cf] = att_s[cf * 16 + li];
    dA[cf] = att_d[cf * 16 + li];
  }

  const bool full = (rowbase + 32) <= M;
#pragma unroll
  for (int rf = 0; rf < 2; ++rf) {
    const int rb = rowbase + rf * 16 + lk * 4;
#pragma unroll
    for (int reg = 0; reg < 4; ++reg) {
      const int r = rb + reg;
      if (full || r < M) {
#pragma unroll
        for (int cf = 0; cf < 8; ++cf)
          hout[(size_t)r * 128 + cf * 16 + li] = (_Float16)acc[rf][cf][reg];
      }
    }
    if constexpr (H == 4) {
#pragma unroll
      for (int hh = 0; hh < 4; ++hh) {
#pragma unroll
        for (int reg = 0; reg < 4; ++reg) {
          float sp = acc[rf][2*hh][reg] * sA[2*hh] + acc[rf][2*hh+1][reg] * sA[2*hh+1];
          float dp = acc[rf][2*hh][reg] * dA[2*hh] + acc[rf][2*hh+1][reg] * dA[2*hh+1];
          sp += __shfl_xor(sp, 1); sp += __shfl_xor(sp, 2);
          sp += __shfl_xor(sp, 4); sp += __shfl_xor(sp, 8);
          dp += __shfl_xor(dp, 1); dp += __shfl_xor(dp, 2);
          dp += __shfl_xor(dp, 4); dp += __shfl_xor(dp, 8);
          const int r = rb + reg;
          if (li == 0 && r < M) {
            a_src[(size_t)r * 4 + hh] = sp;
            a_dst[(size_t)r * 4 + hh] = dp;
          }
        }
      }
    } else {
#pragma unroll
      for (int reg = 0; reg < 4; ++reg) {
        float sp = 0.f, dp = 0.f;
#pragma unroll
        for (int cf = 0; cf < 8; ++cf) {
          sp += acc[rf][cf][reg] * sA[cf];
          dp += acc[rf][cf][reg] * dA[cf];
        }
        sp += __shfl_xor(sp, 1); sp += __shfl_xor(sp, 2);
        sp += __shfl_xor(sp, 4); sp += __shfl_xor(sp, 8);
        dp += __shfl_xor(dp, 1); dp += __shfl_xor(dp, 2);
        dp += __shfl_xor(dp, 4); dp += __shfl_xor(dp, 8);
        const int r = rb + reg;
        if (li == 0 && r < M) { a_src[r] = sp; a_dst[r] = dp; }
      }
    }
  }
}

template<int K, int H, bool A_FP32>
__global__ __launch_bounds__(256)
void gemm_mfma_kernel(const void* __restrict__ Av, const _Float16* __restrict__ BT,
                      const float* __restrict__ att_s, const float* __restrict__ att_d,
                      _Float16* __restrict__ hout, float* __restrict__ a_src,
                      float* __restrict__ a_dst, int M)
{
  gemm_mfma_body<K, H, A_FP32>(blockIdx.x, threadIdx.x, Av, BT, att_s, att_d,
                               hout, a_src, a_dst, M);
}

// ---------------------------------------------------------------------------
// FUSED: XCD-chunked atomic degree count || convW1 || convW2.
// Count blocks [0, NSC): c = bid&7 (dst chunk -> XCD residue), r = bid>>3
// (edge range). deg stripe for chunk c (~25 KB) stays in ONE L2 -> fast atomics.
__global__ __launch_bounds__(256)
void fused_pre_kernel(const int* __restrict__ ei, int E, int N, int epb, int csz,
                      unsigned* __restrict__ deg,
                      const float* __restrict__ W1, _Float16* __restrict__ W1T,
                      const float* __restrict__ W2, _Float16* __restrict__ W2T,
                      int ncount)
{
  const int bid = blockIdx.x;
  if (bid < ncount) {
    const int c = bid & (NXCD - 1);
    const int r = bid >> 3;
    const int dlo = c * csz;
    const int dhi = min(dlo + csz, N);
    const int EE = E + N;
    const int lo = r * epb, hi = min(lo + epb, EE);
    for (int i = lo + threadIdx.x; i < hi; i += 256) {
      int d = (i < E) ? ei[E + i] : (i - E);
      if (d >= dlo && d < dhi) atomicAdd(&deg[d], 1u);
    }
  } else {
    int rem = bid - ncount;
    if (rem < 128) {            // W1: 256x128 = 32768 elems
      int idx = rem * 256 + threadIdx.x;
      int k = idx >> 7, cc = idx & 127;
      W1T[(size_t)cc * 256 + k] = (_Float16)W1[idx];
    } else {                    // W2: 128x128 = 16384 elems
      int idx = (rem - 128) * 256 + threadIdx.x;
      int k = idx >> 7, cc = idx & 127;
      W2T[(size_t)cc * 128 + k] = (_Float16)W2[idx];
    }
  }
}

// Per-512-dst block sums of deg -> bsum. Grid: nblk = ceil(N/512) <= 256.
__global__ __launch_bounds__(256)
void partial_sum_kernel(const unsigned* __restrict__ deg, unsigned* __restrict__ bsum,
                        int N)
{
  __shared__ unsigned red[256];
  const int i = blockIdx.x * 512 + threadIdx.x * 2;
  unsigned s = 0;
  if (i < N)     s += deg[i];
  if (i + 1 < N) s += deg[i + 1];
  red[threadIdx.x] = s;
  __syncthreads();
  for (int o = 128; o; o >>= 1) {
    if (threadIdx.x < o) red[threadIdx.x] += red[threadIdx.x + o];
    __syncthreads();
  }
  if (threadIdx.x == 0) bsum[blockIdx.x] = red[0];
}

// row_start + cursor init, with inline bsum scan. Grid: nblk <= 256.
__global__ __launch_bounds__(256)
void rowstart_kernel(const unsigned* __restrict__ deg, const unsigned* __restrict__ bsum,
                     unsigned* __restrict__ row_start, unsigned* __restrict__ cursor,
                     int N, int nblk)
{
  __shared__ unsigned s[256];
  __shared__ unsigned boff_sh;
  const int t = threadIdx.x;
  unsigned v0 = (t < nblk) ? bsum[t] : 0u;
  s[t] = v0;
  __syncthreads();
  for (int off = 1; off < 256; off <<= 1) {
    unsigned v = (t >= off) ? s[t - off] : 0u;
    __syncthreads();
    s[t] += v;
    __syncthreads();
  }
  if (t == (int)blockIdx.x) boff_sh = s[t] - v0;
  __syncthreads();
  const unsigned boff = boff_sh;
  __syncthreads();
  const int i = blockIdx.x * 512 + t * 2;
  unsigned d0 = (i < N) ? deg[i] : 0u;
  unsigned d1 = (i + 1 < N) ? deg[i + 1] : 0u;
  s[t] = d0 + d1;
  __syncthreads();
  for (int off = 1; off < 256; off <<= 1) {
    unsigned v = (t >= off) ? s[t - off] : 0u;
    __syncthreads();
    s[t] += v;
    __syncthreads();
  }
  unsigned base = boff + s[t] - (d0 + d1);
  if (i < N)     { row_start[i] = base;          cursor[i] = base; }
  if (i + 1 < N) { row_start[i + 1] = base + d0; cursor[i + 1] = base + d0; }
}

// FUSED: gemm layer-1 || XCD-chunked cursor-atomic scatter.
// Scatter blocks: sb = bid - gpad; c = sb&7 -> bid%8 == c (gpad % 8 == 0), so
// cursor stripe (~25 KB) + csr region (~430 KB) of chunk c live in one L2.
__global__ __launch_bounds__(256)
void fused_mid_kernel(const int* __restrict__ ei, int E, int N, int epb, int csz,
                      unsigned* __restrict__ cursor,
                      unsigned* __restrict__ csr_src,
                      const float* __restrict__ x, const _Float16* __restrict__ W1T,
                      const float* __restrict__ as1, const float* __restrict__ ad1,
                      _Float16* __restrict__ h, float* __restrict__ asv,
                      float* __restrict__ adv, int ggrid, int gpad)
{
  const int bid = blockIdx.x;
  if (bid < gpad) {
    if (bid < ggrid)
      gemm_mfma_body<256, 4, true>(bid, threadIdx.x, x, W1T, as1, ad1,
                                   h, asv, adv, N);
  } else {
    const int sb = bid - gpad;
    const int c  = sb & (NXCD - 1);
    const int r  = sb >> 3;
    const int dlo = c * csz;
    const int dhi = min(dlo + csz, N);
    const int EE = E + N;
    const int lo = r * epb, hi = min(lo + epb, EE);
    for (int i = lo + threadIdx.x; i < hi; i += 256) {
      int s, d;
      if (i < E) { s = ei[i]; d = ei[E + i]; } else { s = d = i - E; }
      if (d >= dlo && d < dhi) {
        unsigned pos = atomicAdd(&cursor[d], 1u);
        csr_src[pos] = (unsigned)s;
      }
    }
  }
}

// ---------------------------------------------------------------------------
// Fused per-node aggregation (unchanged).
template<int H, bool OUT_HALF>
__global__ __launch_bounds__(256)
void aggregate_kernel(const unsigned* __restrict__ row_start,
                      const unsigned* __restrict__ deg,
                      const unsigned* __restrict__ csr_src,
                      const __half* __restrict__ h,
                      const float* __restrict__ a_src,
                      const float* __restrict__ a_dst,
                      const float* __restrict__ bias,
                      void* __restrict__ outv, int N)
{
  const int n = blockIdx.x * 4 + (threadIdx.x >> 6);
  if (n >= N) return;
  const int l = threadIdx.x & 63;
  const int hd = (H == 4) ? (l >> 4) : 0;

  const float adn = a_dst[(size_t)n * H + hd];
  const unsigned beg = row_start[n];
  const unsigned cnt = deg[n];              // >= 1 (self loop)
  const __half2* __restrict__ h2 = (const __half2*)h;

  float Z = 0.f, ax = 0.f, ay = 0.f;
  unsigned i = 0;
  for (; i + 4 <= cnt; i += 4) {
    unsigned s0 = csr_src[beg + i];
    unsigned s1 = csr_src[beg + i + 1];
    unsigned s2 = csr_src[beg + i + 2];
    unsigned s3 = csr_src[beg + i + 3];
    float e0 = a_src[(size_t)s0 * H + hd] + adn;
    float e1 = a_src[(size_t)s1 * H + hd] + adn;
    float e2 = a_src[(size_t)s2 * H + hd] + adn;
    float e3 = a_src[(size_t)s3 * H + hd] + adn;
    float2 v0 = __half22float2(h2[(size_t)s0 * 64 + l]);
    float2 v1 = __half22float2(h2[(size_t)s1 * 64 + l]);
    float2 v2 = __half22float2(h2[(size_t)s2 * 64 + l]);
    float2 v3 = __half22float2(h2[(size_t)s3 * 64 + l]);
    e0 = (e0 >= 0.f) ? e0 : SLOPE_ATT * e0;
    e1 = (e1 >= 0.f) ? e1 : SLOPE_ATT * e1;
    e2 = (e2 >= 0.f) ? e2 : SLOPE_ATT * e2;
    e3 = (e3 >= 0.f) ? e3 : SLOPE_ATT * e3;
    float w0 = __expf(e0), w1 = __expf(e1), w2 = __expf(e2), w3 = __expf(e3);
    Z  += (w0 + w1) + (w2 + w3);
    ax += w0 * v0.x + w1 * v1.x + w2 * v2.x + w3 * v3.x;
    ay += w0 * v0.y + w1 * v1.y + w2 * v2.y + w3 * v3.y;
  }
  for (; i < cnt; ++i) {
    unsigned s0 = csr_src[beg + i];
    float e0 = a_src[(size_t)s0 * H + hd] + adn;
    e0 = (e0 >= 0.f) ? e0 : SLOPE_ATT * e0;
    float w0 = __expf(e0);
    float2 v0 = __half22float2(h2[(size_t)s0 * 64 + l]);
    Z  += w0;
    ax += w0 * v0.x;
    ay += w0 * v0.y;
  }
  const float inv = 1.f / (Z + 1e-16f);
  float2 b = ((const float2*)bias)[l];
  float ox = ax * inv + b.x;
  float oy = ay * inv + b.y;
  ox = (ox >= 0.f) ? ox : SLOPE_ACT * ox;
  oy = (oy >= 0.f) ? oy : SLOPE_ACT * oy;
  if constexpr (OUT_HALF)
    ((__half2*)outv)[(size_t)n * 64 + l] = __floats2half2_rn(ox, oy);
  else
    ((float2*)outv)[(size_t)n * 64 + l] = make_float2(ox, oy);
}

// ---------------------------------------------------------------------------
extern "C" void kernel_launch(void* const* d_in, const int* in_sizes, int n_in,
                              void* d_out, int out_size, void* d_ws, size_t ws_size,
                              hipStream_t stream)
{
  const float* x   = (const float*)d_in[0];
  const int*   ei  = (const int*)d_in[1];
  const float* W1  = (const float*)d_in[2];
  const float* as1 = (const float*)d_in[3];
  const float* ad1 = (const float*)d_in[4];
  const float* b1  = (const float*)d_in[5];
  const float* W2  = (const float*)d_in[6];
  const float* as2 = (const float*)d_in[7];
  const float* ad2 = (const float*)d_in[8];
  const float* b2  = (const float*)d_in[9];
  float* out = (float*)d_out;

  const int N  = in_sizes[0] / 256;
  const int E  = in_sizes[1] / 2;
  const int EE = E + N;
  const int nblk = (N + 511) / 512;            // partial_sum/rowstart blocks (<=256)
  const int NSC  = NXCD * NB_CSR;              // count/scatter blocks (1024)
  const int epb  = (EE + NB_CSR - 1) / NB_CSR; // edges per range
  const int csz  = (N + NXCD - 1) / NXCD;      // dst-chunk size

  float* ws = (float*)d_ws;
  size_t o = 0;
  _Float16* h    = (_Float16*)(ws + o); o += (size_t)N * 64;   // [N][128] fp16
  _Float16* act1 = (_Float16*)(ws + o); o += (size_t)N * 64;   // [N][128] fp16
  float* asv = ws + o; o += (size_t)N * 4;
  float* adv = ws + o; o += (size_t)N * 4;
  _Float16* W1T = (_Float16*)(ws + o); o += 128 * 256 / 2;     // [128][256] fp16
  _Float16* W2T = (_Float16*)(ws + o); o += 128 * 128 / 2;     // [128][128] fp16
  unsigned* deg       = (unsigned*)(ws + o); o += (size_t)N;
  unsigned* row_start = (unsigned*)(ws + o); o += (size_t)N;
  unsigned* cursor    = (unsigned*)(ws + o); o += (size_t)N;
  unsigned* bsum      = (unsigned*)(ws + o); o += 256;
  unsigned* csr_src   = (unsigned*)(ws + o); o += (size_t)EE;

  const int ngrid = (N + 3) / 4;
  const int ggrid = (N + 127) / 128;
  const int gpad  = ((ggrid + NXCD - 1) / NXCD) * NXCD;  // %8==0 for scatter residues

  // 0) deg = 0
  hipMemsetAsync(deg, 0, (size_t)N * sizeof(unsigned), stream);
  // 1) chunked atomic count || convW1 || convW2
  fused_pre_kernel<<<NSC + 128 + 64, 256, 0, stream>>>(
      ei, E, N, epb, csz, deg, W1, W1T, W2, W2T, NSC);
  // 2) block sums of deg
  partial_sum_kernel<<<nblk, 256, 0, stream>>>(deg, bsum, N);
  // 3) row starts + cursor init (inline bsum scan)
  rowstart_kernel<<<nblk, 256, 0, stream>>>(deg, bsum, row_start, cursor, N, nblk);
  // 4) gemm layer-1 || chunked cursor-atomic scatter
  fused_mid_kernel<<<gpad + NSC, 256, 0, stream>>>(
      ei, E, N, epb, csz, cursor, csr_src,
      x, W1T, as1, ad1, h, asv, adv, ggrid, gpad);
  // 5) aggregate layer-1 -> act1 (fp16)
  aggregate_kernel<4, true><<<ngrid, 256, 0, stream>>>(
      row_start, deg, csr_src, (const __half*)h, asv, adv, b1, act1, N);
  // 6) gemm layer-2
  gemm_mfma_kernel<128, 1, false><<<ggrid, 256, 0, stream>>>(
      act1, W2T, as2, ad2, h, asv, adv, N);
  // 7) aggregate layer-2 -> out (fp32)
  aggregate_kernel<1, false><<<ngrid, 256, 0, stream>>>(
      row_start, deg, csr_src, (const __half*)h, asv, adv, b2, out, N);
}

// Round 13
// 175.517 us; speedup vs baseline: 1.2458x; 1.2458x over previous
//
#include <hip/hip_runtime.h>
#include <hip/hip_fp16.h>

#define SLOPE_ATT 0.2f
#define SLOPE_ACT 0.01f

#define NB_CSR 128     // edge-range blocks in counting-sort passes
#define CHUNK 8192     // LDS histogram counters per chunk (32 KB -> 5 blk/CU)

typedef _Float16 hf8 __attribute__((ext_vector_type(8)));
typedef float f32x4 __attribute__((ext_vector_type(4)));

// ---------------------------------------------------------------------------
// MFMA fp16 GEMM body: h[M][128] = A[M][K] @ B[K][128], BT[128][K] fp16.
// One wave = 32 rows x 128 cols. No LDS.
template<int K, int H, bool A_FP32>
__device__ __forceinline__
void gemm_mfma_body(int gbid, int tid,
                    const void* __restrict__ Av, const _Float16* __restrict__ BT,
                    const float* __restrict__ att_s, const float* __restrict__ att_d,
                    _Float16* __restrict__ hout, float* __restrict__ a_src,
                    float* __restrict__ a_dst, int M)
{
  const int lane = tid & 63;
  const int wid  = tid >> 6;
  const int li   = lane & 15;
  const int lk   = lane >> 4;
  const int rowbase = gbid * 128 + wid * 32;

  const float*    Af = (const float*)Av;
  const _Float16* Ah = (const _Float16*)Av;

  f32x4 acc[2][8];
#pragma unroll
  for (int i = 0; i < 2; ++i)
#pragma unroll
    for (int j = 0; j < 8; ++j) acc[i][j] = (f32x4){0.f, 0.f, 0.f, 0.f};

  const int r0 = min(rowbase + li,      M - 1);
  const int r1 = min(rowbase + 16 + li, M - 1);

#pragma unroll
  for (int ks = 0; ks < K / 32; ++ks) {
    const int kb = ks * 32 + lk * 8;
    hf8 a0, a1;
    if constexpr (A_FP32) {
      const float* p0 = &Af[(size_t)r0 * K + kb];
      const float* p1 = &Af[(size_t)r1 * K + kb];
      float4 x0a = *(const float4*)p0, x0b = *(const float4*)(p0 + 4);
      float4 x1a = *(const float4*)p1, x1b = *(const float4*)(p1 + 4);
      a0[0]=(_Float16)x0a.x; a0[1]=(_Float16)x0a.y; a0[2]=(_Float16)x0a.z; a0[3]=(_Float16)x0a.w;
      a0[4]=(_Float16)x0b.x; a0[5]=(_Float16)x0b.y; a0[6]=(_Float16)x0b.z; a0[7]=(_Float16)x0b.w;
      a1[0]=(_Float16)x1a.x; a1[1]=(_Float16)x1a.y; a1[2]=(_Float16)x1a.z; a1[3]=(_Float16)x1a.w;
      a1[4]=(_Float16)x1b.x; a1[5]=(_Float16)x1b.y; a1[6]=(_Float16)x1b.z; a1[7]=(_Float16)x1b.w;
    } else {
      a0 = *(const hf8*)&Ah[(size_t)r0 * K + kb];
      a1 = *(const hf8*)&Ah[(size_t)r1 * K + kb];
    }
#pragma unroll
    for (int cf = 0; cf < 8; ++cf) {
      hf8 b = *(const hf8*)&BT[(size_t)(cf * 16 + li) * K + kb];
      acc[0][cf] = __builtin_amdgcn_mfma_f32_16x16x32_f16(a0, b, acc[0][cf], 0, 0, 0);
      acc[1][cf] = __builtin_amdgcn_mfma_f32_16x16x32_f16(a1, b, acc[1][cf], 0, 0, 0);
    }
  }

  float sA[8], dA[8];
#pragma unroll
  for (int cf = 0; cf < 8; ++cf) {
    sA[cf] = att_s[cf * 16 + li];
    dA[cf] = att_d[cf * 16 + li];
  }

  const bool full = (rowbase + 32) <= M;
#pragma unroll
  for (int rf = 0; rf < 2; ++rf) {
    const int rb = rowbase + rf * 16 + lk * 4;
#pragma unroll
    for (int reg = 0; reg < 4; ++reg) {
      const int r = rb + reg;
      if (full || r < M) {
#pragma unroll
        for (int cf = 0; cf < 8; ++cf)
          hout[(size_t)r * 128 + cf * 16 + li] = (_Float16)acc[rf][cf][reg];
      }
    }
    if constexpr (H == 4) {
#pragma unroll
      for (int hh = 0; hh < 4; ++hh) {
#pragma unroll
        for (int reg = 0; reg < 4; ++reg) {
          float sp = acc[rf][2*hh][reg] * sA[2*hh] + acc[rf][2*hh+1][reg] * sA[2*hh+1];
          float dp = acc[rf][2*hh][reg] * dA[2*hh] + acc[rf][2*hh+1][reg] * dA[2*hh+1];
          sp += __shfl_xor(sp, 1); sp += __shfl_xor(sp, 2);
          sp += __shfl_xor(sp, 4); sp += __shfl_xor(sp, 8);
          dp += __shfl_xor(dp, 1); dp += __shfl_xor(dp, 2);
          dp += __shfl_xor(dp, 4); dp += __shfl_xor(dp, 8);
          const int r = rb + reg;
          if (li == 0 && r < M) {
            a_src[(size_t)r * 4 + hh] = sp;
            a_dst[(size_t)r * 4 + hh] = dp;
          }
        }
      }
    } else {
#pragma unroll
      for (int reg = 0; reg < 4; ++reg) {
        float sp = 0.f, dp = 0.f;
#pragma unroll
        for (int cf = 0; cf < 8; ++cf) {
          sp += acc[rf][cf][reg] * sA[cf];
          dp += acc[rf][cf][reg] * dA[cf];
        }
        sp += __shfl_xor(sp, 1); sp += __shfl_xor(sp, 2);
        sp += __shfl_xor(sp, 4); sp += __shfl_xor(sp, 8);
        dp += __shfl_xor(dp, 1); dp += __shfl_xor(dp, 2);
        dp += __shfl_xor(dp, 4); dp += __shfl_xor(dp, 8);
        const int r = rb + reg;
        if (li == 0 && r < M) { a_src[r] = sp; a_dst[r] = dp; }
      }
    }
  }
}

template<int K, int H, bool A_FP32>
__global__ __launch_bounds__(256)
void gemm_mfma_kernel(const void* __restrict__ Av, const _Float16* __restrict__ BT,
                      const float* __restrict__ att_s, const float* __restrict__ att_d,
                      _Float16* __restrict__ hout, float* __restrict__ a_src,
                      float* __restrict__ a_dst, int M)
{
  gemm_mfma_body<K, H, A_FP32>(blockIdx.x, threadIdx.x, Av, BT, att_s, att_d,
                               hout, a_src, a_dst, M);
}

// ---------------------------------------------------------------------------
// FUSED: count (LDS histogram, records per-edge rank) || convW1 || convW2.
__global__ __launch_bounds__(256)
void fused_pre_kernel(const int* __restrict__ ei, int E, int N,
                      unsigned short* __restrict__ cnt16mat,
                      unsigned short* __restrict__ rank16,
                      const float* __restrict__ W1, _Float16* __restrict__ W1T,
                      const float* __restrict__ W2, _Float16* __restrict__ W2T,
                      int ncount)
{
  __shared__ unsigned cnt[CHUNK];
  const int bid = blockIdx.x;
  if (bid < ncount) {
    const int b = bid % NB_CSR;
    const int c0 = (bid / NB_CSR) * CHUNK;
    const int clen = min(CHUNK, N - c0);
    const int EE = E + N;
    const int epb = (EE + NB_CSR - 1) / NB_CSR;
    const int lo = b * epb, hi = min(lo + epb, EE);

    for (int j = threadIdx.x; j < clen; j += 256) cnt[j] = 0;
    __syncthreads();
    for (int i = lo + threadIdx.x; i < hi; i += 256) {
      int d = (i < E) ? ei[E + i] : (i - E);
      int r = d - c0;
      if (r >= 0 && r < clen) {
        unsigned rank = atomicAdd(&cnt[r], 1u);
        rank16[i] = (unsigned short)rank;
      }
    }
    __syncthreads();
    for (int j = threadIdx.x; j < clen; j += 256)
      cnt16mat[(size_t)b * N + c0 + j] = (unsigned short)cnt[j];
  } else {
    int rem = bid - ncount;
    if (rem < 128) {            // W1: 256x128 = 32768 elems
      int idx = rem * 256 + threadIdx.x;
      int k = idx >> 7, c = idx & 127;
      W1T[(size_t)c * 256 + k] = (_Float16)W1[idx];
    } else {                    // W2: 128x128 = 16384 elems
      int idx = (rem - 128) * 256 + threadIdx.x;
      int k = idx >> 7, c = idx & 127;
      W2T[(size_t)c * 128 + k] = (_Float16)W2[idx];
    }
  }
}

// Column scan over blocks per dst (u16, 2 dsts/thread packed) -> deg, bsum.
__global__ __launch_bounds__(256)
void colscan_kernel(unsigned short* __restrict__ cnt16mat,
                    unsigned* __restrict__ deg, unsigned* __restrict__ bsum, int N)
{
  __shared__ unsigned red[256];
  const int d2 = blockIdx.x * 256 + threadIdx.x;   // pair index
  const int N2 = N >> 1;
  unsigned off0 = 0, off1 = 0;
  if (d2 < N2) {
    unsigned* pm = (unsigned*)cnt16mat;
#pragma unroll 8
    for (int b = 0; b < NB_CSR; ++b) {
      unsigned t = pm[(size_t)b * N2 + d2];
      pm[(size_t)b * N2 + d2] = off0 | (off1 << 16);
      off0 += t & 0xFFFFu;
      off1 += t >> 16;
    }
    deg[2 * d2]     = off0;
    deg[2 * d2 + 1] = off1;
  }
  red[threadIdx.x] = off0 + off1;
  __syncthreads();
  for (int o = 128; o; o >>= 1) {
    if (threadIdx.x < o) red[threadIdx.x] += red[threadIdx.x + o];
    __syncthreads();
  }
  if (threadIdx.x == 0) bsum[blockIdx.x] = red[0];
}

// row_start with inline bsum scan. Grid: nblk = ceil(N/512) <= 256.
__global__ __launch_bounds__(256)
void rowstart_kernel(const unsigned* __restrict__ deg, const unsigned* __restrict__ bsum,
                     unsigned* __restrict__ row_start, int N, int nblk)
{
  __shared__ unsigned s[256];
  __shared__ unsigned boff_sh;
  const int t = threadIdx.x;
  unsigned v0 = (t < nblk) ? bsum[t] : 0u;
  s[t] = v0;
  __syncthreads();
  for (int off = 1; off < 256; off <<= 1) {
    unsigned v = (t >= off) ? s[t - off] : 0u;
    __syncthreads();
    s[t] += v;
    __syncthreads();
  }
  if (t == (int)blockIdx.x) boff_sh = s[t] - v0;
  __syncthreads();
  const unsigned boff = boff_sh;
  __syncthreads();
  const int i = blockIdx.x * 512 + t * 2;
  unsigned d0 = (i < N) ? deg[i] : 0u;
  unsigned d1 = (i + 1 < N) ? deg[i + 1] : 0u;
  s[t] = d0 + d1;
  __syncthreads();
  for (int off = 1; off < 256; off <<= 1) {
    unsigned v = (t >= off) ? s[t - off] : 0u;
    __syncthreads();
    s[t] += v;
    __syncthreads();
  }
  unsigned base = boff + s[t] - (d0 + d1);
  if (i < N)     row_start[i] = base;
  if (i + 1 < N) row_start[i + 1] = base + d0;
}

// FUSED (both paths LDS-free): gemm layer-1 || edge-parallel scatter (R9 form).
__global__ __launch_bounds__(256)
void fused_mid_kernel(const int* __restrict__ ei, int E, int N, int epb,
                      const unsigned short* __restrict__ cnt16mat,
                      const unsigned short* __restrict__ rank16,
                      const unsigned* __restrict__ row_start,
                      unsigned* __restrict__ csr_src,
                      const float* __restrict__ x, const _Float16* __restrict__ W1T,
                      const float* __restrict__ as1, const float* __restrict__ ad1,
                      _Float16* __restrict__ h, float* __restrict__ asv,
                      float* __restrict__ adv, int ggrid)
{
  const int bid = blockIdx.x;
  if (bid < ggrid) {
    gemm_mfma_body<256, 4, true>(bid, threadIdx.x, x, W1T, as1, ad1,
                                 h, asv, adv, N);
  } else {
    const int i = (bid - ggrid) * 256 + threadIdx.x;
    const int EE = E + N;
    if (i < EE) {
      int s, d;
      if (i < E) { s = ei[i]; d = ei[E + i]; } else { s = d = i - E; }
      const int b = i / epb;
      unsigned pos = row_start[d] + cnt16mat[(size_t)b * N + d] + rank16[i];
      csr_src[pos] = (unsigned)s;
    }
  }
}

// ---------------------------------------------------------------------------
// Aggregation v2: 16 lanes per node (lane owns 8 features, 16 B), 4 nodes per
// wave, 16 nodes per block. Loop bound = wave-max deg; inactive iterations are
// predicated via clamped index + zero weight (all loads valid, no divergence).
template<int H, bool OUT_HALF>
__global__ __launch_bounds__(256)
void aggregate_kernel(const unsigned* __restrict__ row_start,
                      const unsigned* __restrict__ deg,
                      const unsigned* __restrict__ csr_src,
                      const __half* __restrict__ h,
                      const float* __restrict__ a_src,
                      const float* __restrict__ a_dst,
                      const float* __restrict__ bias,
                      void* __restrict__ outv, int N)
{
  const int lane = threadIdx.x & 63;
  const int wid  = threadIdx.x >> 6;
  const int l5   = lane & 15;                 // lane within node group
  const int n    = blockIdx.x * 16 + wid * 4 + (lane >> 4);
  const int nn   = min(n, N - 1);
  const int hd   = (H == 4) ? (l5 >> 2) : 0;  // features l5*8.. all in head l5>>2

  const float adn = a_dst[(size_t)nn * H + hd];
  const unsigned beg = row_start[nn];
  const unsigned cnt = deg[nn];               // >= 1 (self loop)
  unsigned cmax = cnt;
  cmax = max(cmax, (unsigned)__shfl_xor((int)cmax, 16));
  cmax = max(cmax, (unsigned)__shfl_xor((int)cmax, 32));

  const float4* __restrict__ h4 = (const float4*)h;  // 16 B = 8 fp16

  float Z = 0.f;
  float acc[8];
#pragma unroll
  for (int j = 0; j < 8; ++j) acc[j] = 0.f;

  unsigned i = 0;
  for (; i + 2 <= cmax; i += 2) {
    unsigned s0 = csr_src[beg + min(i,     cnt - 1)];
    unsigned s1 = csr_src[beg + min(i + 1, cnt - 1)];
    float e0 = a_src[(size_t)s0 * H + hd] + adn;
    float e1 = a_src[(size_t)s1 * H + hd] + adn;
    float4 v0 = h4[(size_t)s0 * 16 + l5];
    float4 v1 = h4[(size_t)s1 * 16 + l5];
    e0 = (e0 >= 0.f) ? e0 : SLOPE_ATT * e0;
    e1 = (e1 >= 0.f) ? e1 : SLOPE_ATT * e1;
    float w0 = (i     < cnt) ? __expf(e0) : 0.f;
    float w1 = (i + 1 < cnt) ? __expf(e1) : 0.f;
    Z += w0 + w1;
    const __half2* p0 = (const __half2*)&v0;
    const __half2* p1 = (const __half2*)&v1;
#pragma unroll
    for (int j = 0; j < 4; ++j) {
      float2 f0 = __half22float2(p0[j]);
      float2 f1 = __half22float2(p1[j]);
      acc[2*j]   += w0 * f0.x + w1 * f1.x;
      acc[2*j+1] += w0 * f0.y + w1 * f1.y;
    }
  }
  if (i < cmax) {
    unsigned s0 = csr_src[beg + min(i, cnt - 1)];
    float e0 = a_src[(size_t)s0 * H + hd] + adn;
    float4 v0 = h4[(size_t)s0 * 16 + l5];
    e0 = (e0 >= 0.f) ? e0 : SLOPE_ATT * e0;
    float w0 = (i < cnt) ? __expf(e0) : 0.f;
    Z += w0;
    const __half2* p0 = (const __half2*)&v0;
#pragma unroll
    for (int j = 0; j < 4; ++j) {
      float2 f0 = __half22float2(p0[j]);
      acc[2*j]   += w0 * f0.x;
      acc[2*j+1] += w0 * f0.y;
    }
  }

  const float inv = 1.f / (Z + 1e-16f);
  float4 b0 = ((const float4*)bias)[l5 * 2];
  float4 b1 = ((const float4*)bias)[l5 * 2 + 1];
  float o[8];
  o[0] = acc[0] * inv + b0.x;  o[1] = acc[1] * inv + b0.y;
  o[2] = acc[2] * inv + b0.z;  o[3] = acc[3] * inv + b0.w;
  o[4] = acc[4] * inv + b1.x;  o[5] = acc[5] * inv + b1.y;
  o[6] = acc[6] * inv + b1.z;  o[7] = acc[7] * inv + b1.w;
#pragma unroll
  for (int j = 0; j < 8; ++j) o[j] = (o[j] >= 0.f) ? o[j] : SLOPE_ACT * o[j];

  if (n < N) {
    if constexpr (OUT_HALF) {
      union { __half2 q[4]; float4 f; } u;
      u.q[0] = __floats2half2_rn(o[0], o[1]);
      u.q[1] = __floats2half2_rn(o[2], o[3]);
      u.q[2] = __floats2half2_rn(o[4], o[5]);
      u.q[3] = __floats2half2_rn(o[6], o[7]);
      ((float4*)outv)[(size_t)n * 16 + l5] = u.f;
    } else {
      ((float4*)outv)[(size_t)n * 32 + l5 * 2]     = make_float4(o[0], o[1], o[2], o[3]);
      ((float4*)outv)[(size_t)n * 32 + l5 * 2 + 1] = make_float4(o[4], o[5], o[6], o[7]);
    }
  }
}

// ---------------------------------------------------------------------------
extern "C" void kernel_launch(void* const* d_in, const int* in_sizes, int n_in,
                              void* d_out, int out_size, void* d_ws, size_t ws_size,
                              hipStream_t stream)
{
  const float* x   = (const float*)d_in[0];
  const int*   ei  = (const int*)d_in[1];
  const float* W1  = (const float*)d_in[2];
  const float* as1 = (const float*)d_in[3];
  const float* ad1 = (const float*)d_in[4];
  const float* b1  = (const float*)d_in[5];
  const float* W2  = (const float*)d_in[6];
  const float* as2 = (const float*)d_in[7];
  const float* ad2 = (const float*)d_in[8];
  const float* b2  = (const float*)d_in[9];
  float* out = (float*)d_out;

  const int N  = in_sizes[0] / 256;
  const int E  = in_sizes[1] / 2;
  const int EE = E + N;
  const int NCH  = (N + CHUNK - 1) / CHUNK;    // dst chunks
  const int nblk = (N + 511) / 512;            // colscan/rowstart blocks (<=256)
  const int NSC  = NB_CSR * NCH;               // count blocks
  const int epb  = (EE + NB_CSR - 1) / NB_CSR; // edges per count range

  float* ws = (float*)d_ws;
  size_t o = 0;
  _Float16* h    = (_Float16*)(ws + o); o += (size_t)N * 64;   // [N][128] fp16
  _Float16* act1 = (_Float16*)(ws + o); o += (size_t)N * 64;   // [N][128] fp16
  float* asv = ws + o; o += (size_t)N * 4;
  float* adv = ws + o; o += (size_t)N * 4;
  _Float16* W1T = (_Float16*)(ws + o); o += 128 * 256 / 2;     // [128][256] fp16
  _Float16* W2T = (_Float16*)(ws + o); o += 128 * 128 / 2;     // [128][128] fp16
  unsigned* deg       = (unsigned*)(ws + o); o += (size_t)N;
  unsigned* row_start = (unsigned*)(ws + o); o += (size_t)N;
  unsigned* bsum      = (unsigned*)(ws + o); o += 256;
  unsigned* csr_src   = (unsigned*)(ws + o); o += (size_t)EE;
  unsigned short* cnt16mat = (unsigned short*)(ws + o); o += (size_t)NB_CSR * N / 2; // 12.8 MB
  unsigned short* rank16   = (unsigned short*)(ws + o); o += (size_t)(EE + 1) / 2;   // 1.7 MB

  const int ngrid = (N + 15) / 16;
  const int ggrid = (N + 127) / 128;
  const int sgrid = (EE + 255) / 256;

  // 1) count+rank || convW1 || convW2
  fused_pre_kernel<<<NSC + 128 + 64, 256, 0, stream>>>(
      ei, E, N, cnt16mat, rank16, W1, W1T, W2, W2T, NSC);
  // 2) column scan (packed u16 x2) + block sums
  colscan_kernel<<<nblk, 256, 0, stream>>>(cnt16mat, deg, bsum, N);
  // 3) row starts (inline bsum scan)
  rowstart_kernel<<<nblk, 256, 0, stream>>>(deg, bsum, row_start, N, nblk);
  // 4) gemm layer-1 || edge-parallel scatter
  fused_mid_kernel<<<ggrid + sgrid, 256, 0, stream>>>(
      ei, E, N, epb, cnt16mat, rank16, row_start, csr_src,
      x, W1T, as1, ad1, h, asv, adv, ggrid);
  // 5) aggregate layer-1 -> act1 (fp16)
  aggregate_kernel<4, true><<<ngrid, 256, 0, stream>>>(
      row_start, deg, csr_src, (const __half*)h, asv, adv, b1, act1, N);
  // 6) gemm layer-2
  gemm_mfma_kernel<128, 1, false><<<ggrid, 256, 0, stream>>>(
      act1, W2T, as2, ad2, h, asv, adv, N);
  // 7) aggregate layer-2 -> out (fp32)
  aggregate_kernel<1, false><<<ngrid, 256, 0, stream>>>(
      row_start, deg, csr_src, (const __half*)h, asv, adv, b2, out, N);
}

// Round 14
// 169.953 us; speedup vs baseline: 1.2866x; 1.0327x over previous
//
#include <hip/hip_runtime.h>
#include <hip/hip_fp16.h>

#define SLOPE_ATT 0.2f
#define SLOPE_ACT 0.01f

#define NB_CSR 128     // edge-range blocks in counting-sort passes
#define CHUNK 8192     // LDS histogram counters per chunk (32 KB -> 5 blk/CU)

typedef _Float16 hf8 __attribute__((ext_vector_type(8)));
typedef float f32x4 __attribute__((ext_vector_type(4)));

// ---------------------------------------------------------------------------
// MFMA fp16 GEMM body: h[M][128] = A[M][K] @ B[K][128], BT[128][K] fp16.
// One wave = 32 rows x 128 cols. No LDS.
template<int K, int H, bool A_FP32>
__device__ __forceinline__
void gemm_mfma_body(int gbid, int tid,
                    const void* __restrict__ Av, const _Float16* __restrict__ BT,
                    const float* __restrict__ att_s, const float* __restrict__ att_d,
                    _Float16* __restrict__ hout, float* __restrict__ a_src,
                    float* __restrict__ a_dst, int M)
{
  const int lane = tid & 63;
  const int wid  = tid >> 6;
  const int li   = lane & 15;
  const int lk   = lane >> 4;
  const int rowbase = gbid * 128 + wid * 32;

  const float*    Af = (const float*)Av;
  const _Float16* Ah = (const _Float16*)Av;

  f32x4 acc[2][8];
#pragma unroll
  for (int i = 0; i < 2; ++i)
#pragma unroll
    for (int j = 0; j < 8; ++j) acc[i][j] = (f32x4){0.f, 0.f, 0.f, 0.f};

  const int r0 = min(rowbase + li,      M - 1);
  const int r1 = min(rowbase + 16 + li, M - 1);

#pragma unroll
  for (int ks = 0; ks < K / 32; ++ks) {
    const int kb = ks * 32 + lk * 8;
    hf8 a0, a1;
    if constexpr (A_FP32) {
      const float* p0 = &Af[(size_t)r0 * K + kb];
      const float* p1 = &Af[(size_t)r1 * K + kb];
      float4 x0a = *(const float4*)p0, x0b = *(const float4*)(p0 + 4);
      float4 x1a = *(const float4*)p1, x1b = *(const float4*)(p1 + 4);
      a0[0]=(_Float16)x0a.x; a0[1]=(_Float16)x0a.y; a0[2]=(_Float16)x0a.z; a0[3]=(_Float16)x0a.w;
      a0[4]=(_Float16)x0b.x; a0[5]=(_Float16)x0b.y; a0[6]=(_Float16)x0b.z; a0[7]=(_Float16)x0b.w;
      a1[0]=(_Float16)x1a.x; a1[1]=(_Float16)x1a.y; a1[2]=(_Float16)x1a.z; a1[3]=(_Float16)x1a.w;
      a1[4]=(_Float16)x1b.x; a1[5]=(_Float16)x1b.y; a1[6]=(_Float16)x1b.z; a1[7]=(_Float16)x1b.w;
    } else {
      a0 = *(const hf8*)&Ah[(size_t)r0 * K + kb];
      a1 = *(const hf8*)&Ah[(size_t)r1 * K + kb];
    }
#pragma unroll
    for (int cf = 0; cf < 8; ++cf) {
      hf8 b = *(const hf8*)&BT[(size_t)(cf * 16 + li) * K + kb];
      acc[0][cf] = __builtin_amdgcn_mfma_f32_16x16x32_f16(a0, b, acc[0][cf], 0, 0, 0);
      acc[1][cf] = __builtin_amdgcn_mfma_f32_16x16x32_f16(a1, b, acc[1][cf], 0, 0, 0);
    }
  }

  float sA[8], dA[8];
#pragma unroll
  for (int cf = 0; cf < 8; ++cf) {
    sA[cf] = att_s[cf * 16 + li];
    dA[cf] = att_d[cf * 16 + li];
  }

  const bool full = (rowbase + 32) <= M;
#pragma unroll
  for (int rf = 0; rf < 2; ++rf) {
    const int rb = rowbase + rf * 16 + lk * 4;
#pragma unroll
    for (int reg = 0; reg < 4; ++reg) {
      const int r = rb + reg;
      if (full || r < M) {
#pragma unroll
        for (int cf = 0; cf < 8; ++cf)
          hout[(size_t)r * 128 + cf * 16 + li] = (_Float16)acc[rf][cf][reg];
      }
    }
    if constexpr (H == 4) {
#pragma unroll
      for (int hh = 0; hh < 4; ++hh) {
#pragma unroll
        for (int reg = 0; reg < 4; ++reg) {
          float sp = acc[rf][2*hh][reg] * sA[2*hh] + acc[rf][2*hh+1][reg] * sA[2*hh+1];
          float dp = acc[rf][2*hh][reg] * dA[2*hh] + acc[rf][2*hh+1][reg] * dA[2*hh+1];
          sp += __shfl_xor(sp, 1); sp += __shfl_xor(sp, 2);
          sp += __shfl_xor(sp, 4); sp += __shfl_xor(sp, 8);
          dp += __shfl_xor(dp, 1); dp += __shfl_xor(dp, 2);
          dp += __shfl_xor(dp, 4); dp += __shfl_xor(dp, 8);
          const int r = rb + reg;
          if (li == 0 && r < M) {
            a_src[(size_t)r * 4 + hh] = sp;
            a_dst[(size_t)r * 4 + hh] = dp;
          }
        }
      }
    } else {
#pragma unroll
      for (int reg = 0; reg < 4; ++reg) {
        float sp = 0.f, dp = 0.f;
#pragma unroll
        for (int cf = 0; cf < 8; ++cf) {
          sp += acc[rf][cf][reg] * sA[cf];
          dp += acc[rf][cf][reg] * dA[cf];
        }
        sp += __shfl_xor(sp, 1); sp += __shfl_xor(sp, 2);
        sp += __shfl_xor(sp, 4); sp += __shfl_xor(sp, 8);
        dp += __shfl_xor(dp, 1); dp += __shfl_xor(dp, 2);
        dp += __shfl_xor(dp, 4); dp += __shfl_xor(dp, 8);
        const int r = rb + reg;
        if (li == 0 && r < M) { a_src[r] = sp; a_dst[r] = dp; }
      }
    }
  }
}

// ---------------------------------------------------------------------------
// FUSED: count (LDS histogram, records per-edge rank) || convW1 || convW2.
__global__ __launch_bounds__(256)
void fused_pre_kernel(const int* __restrict__ ei, int E, int N,
                      unsigned short* __restrict__ cnt16mat,
                      unsigned short* __restrict__ rank16,
                      const float* __restrict__ W1, _Float16* __restrict__ W1T,
                      const float* __restrict__ W2, _Float16* __restrict__ W2T,
                      int ncount)
{
  __shared__ unsigned cnt[CHUNK];
  const int bid = blockIdx.x;
  if (bid < ncount) {
    const int b = bid % NB_CSR;
    const int c0 = (bid / NB_CSR) * CHUNK;
    const int clen = min(CHUNK, N - c0);
    const int EE = E + N;
    const int epb = (EE + NB_CSR - 1) / NB_CSR;
    const int lo = b * epb, hi = min(lo + epb, EE);

    for (int j = threadIdx.x; j < clen; j += 256) cnt[j] = 0;
    __syncthreads();
    for (int i = lo + threadIdx.x; i < hi; i += 256) {
      int d = (i < E) ? ei[E + i] : (i - E);
      int r = d - c0;
      if (r >= 0 && r < clen) {
        unsigned rank = atomicAdd(&cnt[r], 1u);
        rank16[i] = (unsigned short)rank;
      }
    }
    __syncthreads();
    for (int j = threadIdx.x; j < clen; j += 256)
      cnt16mat[(size_t)b * N + c0 + j] = (unsigned short)cnt[j];
  } else {
    int rem = bid - ncount;
    if (rem < 128) {            // W1: 256x128 = 32768 elems
      int idx = rem * 256 + threadIdx.x;
      int k = idx >> 7, c = idx & 127;
      W1T[(size_t)c * 256 + k] = (_Float16)W1[idx];
    } else {                    // W2: 128x128 = 16384 elems
      int idx = (rem - 128) * 256 + threadIdx.x;
      int k = idx >> 7, c = idx & 127;
      W2T[(size_t)c * 128 + k] = (_Float16)W2[idx];
    }
  }
}

// Column scan over blocks per dst (u16, 2 dsts/thread packed) -> deg, bsum.
__global__ __launch_bounds__(256)
void colscan_kernel(unsigned short* __restrict__ cnt16mat,
                    unsigned* __restrict__ deg, unsigned* __restrict__ bsum, int N)
{
  __shared__ unsigned red[256];
  const int d2 = blockIdx.x * 256 + threadIdx.x;   // pair index
  const int N2 = N >> 1;
  unsigned off0 = 0, off1 = 0;
  if (d2 < N2) {
    unsigned* pm = (unsigned*)cnt16mat;
#pragma unroll 8
    for (int b = 0; b < NB_CSR; ++b) {
      unsigned t = pm[(size_t)b * N2 + d2];
      pm[(size_t)b * N2 + d2] = off0 | (off1 << 16);
      off0 += t & 0xFFFFu;
      off1 += t >> 16;
    }
    deg[2 * d2]     = off0;
    deg[2 * d2 + 1] = off1;
  }
  red[threadIdx.x] = off0 + off1;
  __syncthreads();
  for (int o = 128; o; o >>= 1) {
    if (threadIdx.x < o) red[threadIdx.x] += red[threadIdx.x + o];
    __syncthreads();
  }
  if (threadIdx.x == 0) bsum[blockIdx.x] = red[0];
}

// row_start with inline bsum scan. Grid: nblk = ceil(N/512) <= 256.
__global__ __launch_bounds__(256)
void rowstart_kernel(const unsigned* __restrict__ deg, const unsigned* __restrict__ bsum,
                     unsigned* __restrict__ row_start, int N, int nblk)
{
  __shared__ unsigned s[256];
  __shared__ unsigned boff_sh;
  const int t = threadIdx.x;
  unsigned v0 = (t < nblk) ? bsum[t] : 0u;
  s[t] = v0;
  __syncthreads();
  for (int off = 1; off < 256; off <<= 1) {
    unsigned v = (t >= off) ? s[t - off] : 0u;
    __syncthreads();
    s[t] += v;
    __syncthreads();
  }
  if (t == (int)blockIdx.x) boff_sh = s[t] - v0;
  __syncthreads();
  const unsigned boff = boff_sh;
  __syncthreads();
  const int i = blockIdx.x * 512 + t * 2;
  unsigned d0 = (i < N) ? deg[i] : 0u;
  unsigned d1 = (i + 1 < N) ? deg[i + 1] : 0u;
  s[t] = d0 + d1;
  __syncthreads();
  for (int off = 1; off < 256; off <<= 1) {
    unsigned v = (t >= off) ? s[t - off] : 0u;
    __syncthreads();
    s[t] += v;
    __syncthreads();
  }
  unsigned base = boff + s[t] - (d0 + d1);
  if (i < N)     row_start[i] = base;
  if (i + 1 < N) row_start[i + 1] = base + d0;
}

// FUSED (both paths LDS-free): gemm layer-1 || edge-parallel scatter.
__global__ __launch_bounds__(256)
void fused_mid_kernel(const int* __restrict__ ei, int E, int N, int epb,
                      const unsigned short* __restrict__ cnt16mat,
                      const unsigned short* __restrict__ rank16,
                      const unsigned* __restrict__ row_start,
                      unsigned* __restrict__ csr_src,
                      const float* __restrict__ x, const _Float16* __restrict__ W1T,
                      const float* __restrict__ as1, const float* __restrict__ ad1,
                      _Float16* __restrict__ h, float* __restrict__ asv,
                      float* __restrict__ adv, int ggrid)
{
  const int bid = blockIdx.x;
  if (bid < ggrid) {
    gemm_mfma_body<256, 4, true>(bid, threadIdx.x, x, W1T, as1, ad1,
                                 h, asv, adv, N);
  } else {
    const int i = (bid - ggrid) * 256 + threadIdx.x;
    const int EE = E + N;
    if (i < EE) {
      int s, d;
      if (i < E) { s = ei[i]; d = ei[E + i]; } else { s = d = i - E; }
      const int b = i / epb;
      unsigned pos = row_start[d] + cnt16mat[(size_t)b * N + d] + rank16[i];
      csr_src[pos] = (unsigned)s;
    }
  }
}

// ---------------------------------------------------------------------------
// FUSED aggregate layer-1 + gemm layer-2 + layer-2 att dots.
// Phase 1: aggregate v2 (16 lanes/node, 4 nodes/wave, 16 nodes/block).
// Phase 2: stage act1 tile (16x128 fp16) in LDS.
// Phase 3: per-wave 16x32-col MFMA slice of h2 = act1 @ W2 with fused
//          H=1 att dots (shfl reduce over 16 lanes + LDS fp32 atomics).
__global__ __launch_bounds__(256)
void agg1_gemm2_kernel(const unsigned* __restrict__ row_start,
                       const unsigned* __restrict__ deg,
                       const unsigned* __restrict__ csr_src,
                       const __half* __restrict__ h,
                       const float* __restrict__ a_src,
                       const float* __restrict__ a_dst,
                       const float* __restrict__ bias,
                       const _Float16* __restrict__ W2T,
                       const float* __restrict__ as2, const float* __restrict__ ad2,
                       _Float16* __restrict__ h2,
                       float* __restrict__ asv2, float* __restrict__ adv2, int N)
{
  __shared__ _Float16 actS[16][136];   // row stride 272 B: 16B-aligned, 2-way banks
  __shared__ float sdots[2][16];

  const int lane = threadIdx.x & 63;
  const int wid  = threadIdx.x >> 6;
  const int l5   = lane & 15;
  const int nl   = wid * 4 + (lane >> 4);     // node local 0..15
  const int nb   = blockIdx.x * 16;
  const int n    = nb + nl;
  const int nn   = min(n, N - 1);
  const int hd   = l5 >> 2;                   // H=4 head for this lane's feats

  // ---------------- phase 1: aggregate (H=4) ----------------
  const float adn = a_dst[(size_t)nn * 4 + hd];
  const unsigned beg = row_start[nn];
  const unsigned cnt = deg[nn];               // >= 1 (self loop)
  unsigned cmax = cnt;
  cmax = max(cmax, (unsigned)__shfl_xor((int)cmax, 16));
  cmax = max(cmax, (unsigned)__shfl_xor((int)cmax, 32));

  const float4* __restrict__ h4 = (const float4*)h;

  float Z = 0.f;
  float acc[8];
#pragma unroll
  for (int j = 0; j < 8; ++j) acc[j] = 0.f;

  unsigned i = 0;
  for (; i + 2 <= cmax; i += 2) {
    unsigned s0 = csr_src[beg + min(i,     cnt - 1)];
    unsigned s1 = csr_src[beg + min(i + 1, cnt - 1)];
    float e0 = a_src[(size_t)s0 * 4 + hd] + adn;
    float e1 = a_src[(size_t)s1 * 4 + hd] + adn;
    float4 v0 = h4[(size_t)s0 * 16 + l5];
    float4 v1 = h4[(size_t)s1 * 16 + l5];
    e0 = (e0 >= 0.f) ? e0 : SLOPE_ATT * e0;
    e1 = (e1 >= 0.f) ? e1 : SLOPE_ATT * e1;
    float w0 = (i     < cnt) ? __expf(e0) : 0.f;
    float w1 = (i + 1 < cnt) ? __expf(e1) : 0.f;
    Z += w0 + w1;
    const __half2* p0 = (const __half2*)&v0;
    const __half2* p1 = (const __half2*)&v1;
#pragma unroll
    for (int j = 0; j < 4; ++j) {
      float2 f0 = __half22float2(p0[j]);
      float2 f1 = __half22float2(p1[j]);
      acc[2*j]   += w0 * f0.x + w1 * f1.x;
      acc[2*j+1] += w0 * f0.y + w1 * f1.y;
    }
  }
  if (i < cmax) {
    unsigned s0 = csr_src[beg + min(i, cnt - 1)];
    float e0 = a_src[(size_t)s0 * 4 + hd] + adn;
    float4 v0 = h4[(size_t)s0 * 16 + l5];
    e0 = (e0 >= 0.f) ? e0 : SLOPE_ATT * e0;
    float w0 = (i < cnt) ? __expf(e0) : 0.f;
    Z += w0;
    const __half2* p0 = (const __half2*)&v0;
#pragma unroll
    for (int j = 0; j < 4; ++j) {
      float2 f0 = __half22float2(p0[j]);
      acc[2*j]   += w0 * f0.x;
      acc[2*j+1] += w0 * f0.y;
    }
  }

  const float inv = 1.f / (Z + 1e-16f);
  float4 b0 = ((const float4*)bias)[l5 * 2];
  float4 b1 = ((const float4*)bias)[l5 * 2 + 1];
  float o[8];
  o[0] = acc[0] * inv + b0.x;  o[1] = acc[1] * inv + b0.y;
  o[2] = acc[2] * inv + b0.z;  o[3] = acc[3] * inv + b0.w;
  o[4] = acc[4] * inv + b1.x;  o[5] = acc[5] * inv + b1.y;
  o[6] = acc[6] * inv + b1.z;  o[7] = acc[7] * inv + b1.w;
#pragma unroll
  for (int j = 0; j < 8; ++j) o[j] = (o[j] >= 0.f) ? o[j] : SLOPE_ACT * o[j];

  // ---------------- phase 2: stage act1 to LDS ----------------
#pragma unroll
  for (int j = 0; j < 8; ++j) actS[nl][l5 * 8 + j] = (_Float16)o[j];
  if (threadIdx.x < 32) sdots[threadIdx.x >> 4][threadIdx.x & 15] = 0.f;
  __syncthreads();

  // ---------------- phase 3: mini-GEMM h2 = act1 @ W2 ----------------
  const int li = l5;
  const int lk = lane >> 4;
#pragma unroll
  for (int t = 0; t < 2; ++t) {
    const int c0 = wid * 32 + t * 16;
    f32x4 a2 = (f32x4){0.f, 0.f, 0.f, 0.f};
#pragma unroll
    for (int ks = 0; ks < 4; ++ks) {
      hf8 af = *(const hf8*)&actS[li][ks * 32 + lk * 8];
      hf8 bf = *(const hf8*)&W2T[(size_t)(c0 + li) * 128 + ks * 32 + lk * 8];
      a2 = __builtin_amdgcn_mfma_f32_16x16x32_f16(af, bf, a2, 0, 0, 0);
    }
    const float asc = as2[c0 + li];
    const float adc = ad2[c0 + li];
#pragma unroll
    for (int reg = 0; reg < 4; ++reg) {
      const int r = lk * 4 + reg;           // node local
      float hv = a2[reg];
      if (nb + r < N) h2[(size_t)(nb + r) * 128 + c0 + li] = (_Float16)hv;
      float sp = hv * asc;
      float dp = hv * adc;
      sp += __shfl_xor(sp, 1); sp += __shfl_xor(sp, 2);
      sp += __shfl_xor(sp, 4); sp += __shfl_xor(sp, 8);
      dp += __shfl_xor(dp, 1); dp += __shfl_xor(dp, 2);
      dp += __shfl_xor(dp, 4); dp += __shfl_xor(dp, 8);
      if (li == 0) {
        atomicAdd(&sdots[0][r], sp);
        atomicAdd(&sdots[1][r], dp);
      }
    }
  }
  __syncthreads();
  if (threadIdx.x < 16) {
    const int r = threadIdx.x;
    if (nb + r < N) {
      asv2[nb + r] = sdots[0][r];
      adv2[nb + r] = sdots[1][r];
    }
  }
}

// ---------------------------------------------------------------------------
// Aggregation v2 (H=1, fp32 out) for layer 2 -> d_out.
__global__ __launch_bounds__(256)
void aggregate2_kernel(const unsigned* __restrict__ row_start,
                       const unsigned* __restrict__ deg,
                       const unsigned* __restrict__ csr_src,
                       const __half* __restrict__ h,
                       const float* __restrict__ a_src,
                       const float* __restrict__ a_dst,
                       const float* __restrict__ bias,
                       float* __restrict__ out, int N)
{
  const int lane = threadIdx.x & 63;
  const int wid  = threadIdx.x >> 6;
  const int l5   = lane & 15;
  const int n    = blockIdx.x * 16 + wid * 4 + (lane >> 4);
  const int nn   = min(n, N - 1);

  const float adn = a_dst[nn];
  const unsigned beg = row_start[nn];
  const unsigned cnt = deg[nn];
  unsigned cmax = cnt;
  cmax = max(cmax, (unsigned)__shfl_xor((int)cmax, 16));
  cmax = max(cmax, (unsigned)__shfl_xor((int)cmax, 32));

  const float4* __restrict__ h4 = (const float4*)h;

  float Z = 0.f;
  float acc[8];
#pragma unroll
  for (int j = 0; j < 8; ++j) acc[j] = 0.f;

  unsigned i = 0;
  for (; i + 2 <= cmax; i += 2) {
    unsigned s0 = csr_src[beg + min(i,     cnt - 1)];
    unsigned s1 = csr_src[beg + min(i + 1, cnt - 1)];
    float e0 = a_src[s0] + adn;
    float e1 = a_src[s1] + adn;
    float4 v0 = h4[(size_t)s0 * 16 + l5];
    float4 v1 = h4[(size_t)s1 * 16 + l5];
    e0 = (e0 >= 0.f) ? e0 : SLOPE_ATT * e0;
    e1 = (e1 >= 0.f) ? e1 : SLOPE_ATT * e1;
    float w0 = (i     < cnt) ? __expf(e0) : 0.f;
    float w1 = (i + 1 < cnt) ? __expf(e1) : 0.f;
    Z += w0 + w1;
    const __half2* p0 = (const __half2*)&v0;
    const __half2* p1 = (const __half2*)&v1;
#pragma unroll
    for (int j = 0; j < 4; ++j) {
      float2 f0 = __half22float2(p0[j]);
      float2 f1 = __half22float2(p1[j]);
      acc[2*j]   += w0 * f0.x + w1 * f1.x;
      acc[2*j+1] += w0 * f0.y + w1 * f1.y;
    }
  }
  if (i < cmax) {
    unsigned s0 = csr_src[beg + min(i, cnt - 1)];
    float e0 = a_src[s0] + adn;
    float4 v0 = h4[(size_t)s0 * 16 + l5];
    e0 = (e0 >= 0.f) ? e0 : SLOPE_ATT * e0;
    float w0 = (i < cnt) ? __expf(e0) : 0.f;
    Z += w0;
    const __half2* p0 = (const __half2*)&v0;
#pragma unroll
    for (int j = 0; j < 4; ++j) {
      float2 f0 = __half22float2(p0[j]);
      acc[2*j]   += w0 * f0.x;
      acc[2*j+1] += w0 * f0.y;
    }
  }

  const float inv = 1.f / (Z + 1e-16f);
  float4 b0 = ((const float4*)bias)[l5 * 2];
  float4 b1 = ((const float4*)bias)[l5 * 2 + 1];
  float o[8];
  o[0] = acc[0] * inv + b0.x;  o[1] = acc[1] * inv + b0.y;
  o[2] = acc[2] * inv + b0.z;  o[3] = acc[3] * inv + b0.w;
  o[4] = acc[4] * inv + b1.x;  o[5] = acc[5] * inv + b1.y;
  o[6] = acc[6] * inv + b1.z;  o[7] = acc[7] * inv + b1.w;
#pragma unroll
  for (int j = 0; j < 8; ++j) o[j] = (o[j] >= 0.f) ? o[j] : SLOPE_ACT * o[j];

  if (n < N) {
    ((float4*)out)[(size_t)n * 32 + l5 * 2]     = make_float4(o[0], o[1], o[2], o[3]);
    ((float4*)out)[(size_t)n * 32 + l5 * 2 + 1] = make_float4(o[4], o[5], o[6], o[7]);
  }
}

// ---------------------------------------------------------------------------
extern "C" void kernel_launch(void* const* d_in, const int* in_sizes, int n_in,
                              void* d_out, int out_size, void* d_ws, size_t ws_size,
                              hipStream_t stream)
{
  const float* x   = (const float*)d_in[0];
  const int*   ei  = (const int*)d_in[1];
  const float* W1  = (const float*)d_in[2];
  const float* as1 = (const float*)d_in[3];
  const float* ad1 = (const float*)d_in[4];
  const float* b1  = (const float*)d_in[5];
  const float* W2  = (const float*)d_in[6];
  const float* as2 = (const float*)d_in[7];
  const float* ad2 = (const float*)d_in[8];
  const float* b2  = (const float*)d_in[9];
  float* out = (float*)d_out;

  const int N  = in_sizes[0] / 256;
  const int E  = in_sizes[1] / 2;
  const int EE = E + N;
  const int NCH  = (N + CHUNK - 1) / CHUNK;    // dst chunks
  const int nblk = (N + 511) / 512;            // colscan/rowstart blocks (<=256)
  const int NSC  = NB_CSR * NCH;               // count blocks
  const int epb  = (EE + NB_CSR - 1) / NB_CSR; // edges per count range

  float* ws = (float*)d_ws;
  size_t o = 0;
  _Float16* h    = (_Float16*)(ws + o); o += (size_t)N * 64;   // layer-1 h [N][128] fp16
  _Float16* h2   = (_Float16*)(ws + o); o += (size_t)N * 64;   // layer-2 h [N][128] fp16
  float* asv  = ws + o; o += (size_t)N * 4;                    // layer-1 dots (H=4)
  float* adv  = ws + o; o += (size_t)N * 4;
  float* asv2 = ws + o; o += (size_t)N;                        // layer-2 dots (H=1)
  float* adv2 = ws + o; o += (size_t)N;
  _Float16* W1T = (_Float16*)(ws + o); o += 128 * 256 / 2;     // [128][256] fp16
  _Float16* W2T = (_Float16*)(ws + o); o += 128 * 128 / 2;     // [128][128] fp16
  unsigned* deg       = (unsigned*)(ws + o); o += (size_t)N;
  unsigned* row_start = (unsigned*)(ws + o); o += (size_t)N;
  unsigned* bsum      = (unsigned*)(ws + o); o += 256;
  unsigned* csr_src   = (unsigned*)(ws + o); o += (size_t)EE;
  unsigned short* cnt16mat = (unsigned short*)(ws + o); o += (size_t)NB_CSR * N / 2; // 12.8 MB
  unsigned short* rank16   = (unsigned short*)(ws + o); o += (size_t)(EE + 1) / 2;   // 1.7 MB

  const int ngrid = (N + 15) / 16;
  const int ggrid = (N + 127) / 128;
  const int sgrid = (EE + 255) / 256;

  // 1) count+rank || convW1 || convW2
  fused_pre_kernel<<<NSC + 128 + 64, 256, 0, stream>>>(
      ei, E, N, cnt16mat, rank16, W1, W1T, W2, W2T, NSC);
  // 2) column scan (packed u16 x2) + block sums
  colscan_kernel<<<nblk, 256, 0, stream>>>(cnt16mat, deg, bsum, N);
  // 3) row starts (inline bsum scan)
  rowstart_kernel<<<nblk, 256, 0, stream>>>(deg, bsum, row_start, N, nblk);
  // 4) gemm layer-1 || edge-parallel scatter
  fused_mid_kernel<<<ggrid + sgrid, 256, 0, stream>>>(
      ei, E, N, epb, cnt16mat, rank16, row_start, csr_src,
      x, W1T, as1, ad1, h, asv, adv, ggrid);
  // 5) aggregate layer-1 + gemm layer-2 + layer-2 dots (fused)
  agg1_gemm2_kernel<<<ngrid, 256, 0, stream>>>(
      row_start, deg, csr_src, (const __half*)h, asv, adv, b1,
      W2T, as2, ad2, h2, asv2, adv2, N);
  // 6) aggregate layer-2 -> out (fp32)
  aggregate2_kernel<<<ngrid, 256, 0, stream>>>(
      row_start, deg, csr_src, (const __half*)h2, asv2, adv2, b2, out, N);
}

// Round 15
// 168.747 us; speedup vs baseline: 1.2958x; 1.0071x over previous
//
#include <hip/hip_runtime.h>
#include <hip/hip_fp16.h>

#define SLOPE_ATT 0.2f
#define SLOPE_ACT 0.01f

#define NB_CSR 128     // edge-range blocks in counting-sort passes
#define CHUNK 8192     // LDS histogram counters per chunk (32 KB -> 5 blk/CU)

typedef _Float16 hf8 __attribute__((ext_vector_type(8)));
typedef float f32x4 __attribute__((ext_vector_type(4)));

// ---------------------------------------------------------------------------
// MFMA fp16 GEMM body: h[M][128] = A[M][K] @ B[K][128], BT[128][K] fp16.
// One wave = 32 rows x 128 cols. No LDS.
template<int K, int H, bool A_FP32>
__device__ __forceinline__
void gemm_mfma_body(int gbid, int tid,
                    const void* __restrict__ Av, const _Float16* __restrict__ BT,
                    const float* __restrict__ att_s, const float* __restrict__ att_d,
                    _Float16* __restrict__ hout, float* __restrict__ a_src,
                    float* __restrict__ a_dst, int M)
{
  const int lane = tid & 63;
  const int wid  = tid >> 6;
  const int li   = lane & 15;
  const int lk   = lane >> 4;
  const int rowbase = gbid * 128 + wid * 32;

  const float*    Af = (const float*)Av;
  const _Float16* Ah = (const _Float16*)Av;

  f32x4 acc[2][8];
#pragma unroll
  for (int i = 0; i < 2; ++i)
#pragma unroll
    for (int j = 0; j < 8; ++j) acc[i][j] = (f32x4){0.f, 0.f, 0.f, 0.f};

  const int r0 = min(rowbase + li,      M - 1);
  const int r1 = min(rowbase + 16 + li, M - 1);

#pragma unroll
  for (int ks = 0; ks < K / 32; ++ks) {
    const int kb = ks * 32 + lk * 8;
    hf8 a0, a1;
    if constexpr (A_FP32) {
      const float* p0 = &Af[(size_t)r0 * K + kb];
      const float* p1 = &Af[(size_t)r1 * K + kb];
      float4 x0a = *(const float4*)p0, x0b = *(const float4*)(p0 + 4);
      float4 x1a = *(const float4*)p1, x1b = *(const float4*)(p1 + 4);
      a0[0]=(_Float16)x0a.x; a0[1]=(_Float16)x0a.y; a0[2]=(_Float16)x0a.z; a0[3]=(_Float16)x0a.w;
      a0[4]=(_Float16)x0b.x; a0[5]=(_Float16)x0b.y; a0[6]=(_Float16)x0b.z; a0[7]=(_Float16)x0b.w;
      a1[0]=(_Float16)x1a.x; a1[1]=(_Float16)x1a.y; a1[2]=(_Float16)x1a.z; a1[3]=(_Float16)x1a.w;
      a1[4]=(_Float16)x1b.x; a1[5]=(_Float16)x1b.y; a1[6]=(_Float16)x1b.z; a1[7]=(_Float16)x1b.w;
    } else {
      a0 = *(const hf8*)&Ah[(size_t)r0 * K + kb];
      a1 = *(const hf8*)&Ah[(size_t)r1 * K + kb];
    }
#pragma unroll
    for (int cf = 0; cf < 8; ++cf) {
      hf8 b = *(const hf8*)&BT[(size_t)(cf * 16 + li) * K + kb];
      acc[0][cf] = __builtin_amdgcn_mfma_f32_16x16x32_f16(a0, b, acc[0][cf], 0, 0, 0);
      acc[1][cf] = __builtin_amdgcn_mfma_f32_16x16x32_f16(a1, b, acc[1][cf], 0, 0, 0);
    }
  }

  float sA[8], dA[8];
#pragma unroll
  for (int cf = 0; cf < 8; ++cf) {
    sA[cf] = att_s[cf * 16 + li];
    dA[cf] = att_d[cf * 16 + li];
  }

  const bool full = (rowbase + 32) <= M;
#pragma unroll
  for (int rf = 0; rf < 2; ++rf) {
    const int rb = rowbase + rf * 16 + lk * 4;
#pragma unroll
    for (int reg = 0; reg < 4; ++reg) {
      const int r = rb + reg;
      if (full || r < M) {
#pragma unroll
        for (int cf = 0; cf < 8; ++cf)
          hout[(size_t)r * 128 + cf * 16 + li] = (_Float16)acc[rf][cf][reg];
      }
    }
    if constexpr (H == 4) {
#pragma unroll
      for (int hh = 0; hh < 4; ++hh) {
#pragma unroll
        for (int reg = 0; reg < 4; ++reg) {
          float sp = acc[rf][2*hh][reg] * sA[2*hh] + acc[rf][2*hh+1][reg] * sA[2*hh+1];
          float dp = acc[rf][2*hh][reg] * dA[2*hh] + acc[rf][2*hh+1][reg] * dA[2*hh+1];
          sp += __shfl_xor(sp, 1); sp += __shfl_xor(sp, 2);
          sp += __shfl_xor(sp, 4); sp += __shfl_xor(sp, 8);
          dp += __shfl_xor(dp, 1); dp += __shfl_xor(dp, 2);
          dp += __shfl_xor(dp, 4); dp += __shfl_xor(dp, 8);
          const int r = rb + reg;
          if (li == 0 && r < M) {
            a_src[(size_t)r * 4 + hh] = sp;
            a_dst[(size_t)r * 4 + hh] = dp;
          }
        }
      }
    } else {
#pragma unroll
      for (int reg = 0; reg < 4; ++reg) {
        float sp = 0.f, dp = 0.f;
#pragma unroll
        for (int cf = 0; cf < 8; ++cf) {
          sp += acc[rf][cf][reg] * sA[cf];
          dp += acc[rf][cf][reg] * dA[cf];
        }
        sp += __shfl_xor(sp, 1); sp += __shfl_xor(sp, 2);
        sp += __shfl_xor(sp, 4); sp += __shfl_xor(sp, 8);
        dp += __shfl_xor(dp, 1); dp += __shfl_xor(dp, 2);
        dp += __shfl_xor(dp, 4); dp += __shfl_xor(dp, 8);
        const int r = rb + reg;
        if (li == 0 && r < M) { a_src[r] = sp; a_dst[r] = dp; }
      }
    }
  }
}

// ---------------------------------------------------------------------------
// FUSED: count (LDS histogram, records per-edge rank) || convW1 || convW2
//        || sd32 edge packing ((src<<16)|dst, u16 fields; N < 65536).
__global__ __launch_bounds__(256)
void fused_pre_kernel(const int* __restrict__ ei, int E, int N,
                      unsigned short* __restrict__ cnt16mat,
                      unsigned short* __restrict__ rank16,
                      unsigned* __restrict__ sd32,
                      const float* __restrict__ W1, _Float16* __restrict__ W1T,
                      const float* __restrict__ W2, _Float16* __restrict__ W2T,
                      int ncount)
{
  __shared__ unsigned cnt[CHUNK];
  const int bid = blockIdx.x;
  if (bid < ncount) {
    const int b = bid % NB_CSR;
    const int c0 = (bid / NB_CSR) * CHUNK;
    const int clen = min(CHUNK, N - c0);
    const int EE = E + N;
    const int epb = (EE + NB_CSR - 1) / NB_CSR;
    const int lo = b * epb, hi = min(lo + epb, EE);

    for (int j = threadIdx.x; j < clen; j += 256) cnt[j] = 0;
    __syncthreads();
    for (int i = lo + threadIdx.x; i < hi; i += 256) {
      int d = (i < E) ? ei[E + i] : (i - E);
      int r = d - c0;
      if (r >= 0 && r < clen) {
        unsigned rank = atomicAdd(&cnt[r], 1u);
        rank16[i] = (unsigned short)rank;
      }
    }
    __syncthreads();
    for (int j = threadIdx.x; j < clen; j += 256)
      cnt16mat[(size_t)b * N + c0 + j] = (unsigned short)cnt[j];
  } else {
    int rem = bid - ncount;
    if (rem < 128) {            // W1: 256x128 = 32768 elems
      int idx = rem * 256 + threadIdx.x;
      int k = idx >> 7, c = idx & 127;
      W1T[(size_t)c * 256 + k] = (_Float16)W1[idx];
    } else if (rem < 192) {     // W2: 128x128 = 16384 elems
      int idx = (rem - 128) * 256 + threadIdx.x;
      int k = idx >> 7, c = idx & 127;
      W2T[(size_t)c * 128 + k] = (_Float16)W2[idx];
    } else {                    // edge packing
      const int i = (rem - 192) * 256 + threadIdx.x;
      const int EE = E + N;
      if (i < EE) {
        unsigned s, d;
        if (i < E) { s = (unsigned)ei[i]; d = (unsigned)ei[E + i]; }
        else       { s = d = (unsigned)(i - E); }
        sd32[i] = (s << 16) | d;
      }
    }
  }
}

// Column scan over blocks per dst (u16, 2 dsts/thread packed) -> deg, bsum.
__global__ __launch_bounds__(256)
void colscan_kernel(unsigned short* __restrict__ cnt16mat,
                    unsigned* __restrict__ deg, unsigned* __restrict__ bsum, int N)
{
  __shared__ unsigned red[256];
  const int d2 = blockIdx.x * 256 + threadIdx.x;   // pair index
  const int N2 = N >> 1;
  unsigned off0 = 0, off1 = 0;
  if (d2 < N2) {
    unsigned* pm = (unsigned*)cnt16mat;
#pragma unroll 8
    for (int b = 0; b < NB_CSR; ++b) {
      unsigned t = pm[(size_t)b * N2 + d2];
      pm[(size_t)b * N2 + d2] = off0 | (off1 << 16);
      off0 += t & 0xFFFFu;
      off1 += t >> 16;
    }
    deg[2 * d2]     = off0;
    deg[2 * d2 + 1] = off1;
  }
  red[threadIdx.x] = off0 + off1;
  __syncthreads();
  for (int o = 128; o; o >>= 1) {
    if (threadIdx.x < o) red[threadIdx.x] += red[threadIdx.x + o];
    __syncthreads();
  }
  if (threadIdx.x == 0) bsum[blockIdx.x] = red[0];
}

// row_start with inline bsum scan. Grid: nblk = ceil(N/512) <= 256.
__global__ __launch_bounds__(256)
void rowstart_kernel(const unsigned* __restrict__ deg, const unsigned* __restrict__ bsum,
                     unsigned* __restrict__ row_start, int N, int nblk)
{
  __shared__ unsigned s[256];
  __shared__ unsigned boff_sh;
  const int t = threadIdx.x;
  unsigned v0 = (t < nblk) ? bsum[t] : 0u;
  s[t] = v0;
  __syncthreads();
  for (int off = 1; off < 256; off <<= 1) {
    unsigned v = (t >= off) ? s[t - off] : 0u;
    __syncthreads();
    s[t] += v;
    __syncthreads();
  }
  if (t == (int)blockIdx.x) boff_sh = s[t] - v0;
  __syncthreads();
  const unsigned boff = boff_sh;
  __syncthreads();
  const int i = blockIdx.x * 512 + t * 2;
  unsigned d0 = (i < N) ? deg[i] : 0u;
  unsigned d1 = (i + 1 < N) ? deg[i + 1] : 0u;
  s[t] = d0 + d1;
  __syncthreads();
  for (int off = 1; off < 256; off <<= 1) {
    unsigned v = (t >= off) ? s[t - off] : 0u;
    __syncthreads();
    s[t] += v;
    __syncthreads();
  }
  unsigned base = boff + s[t] - (d0 + d1);
  if (i < N)     row_start[i] = base;
  if (i + 1 < N) row_start[i + 1] = base + d0;
}

// FUSED (both paths LDS-free): gemm layer-1 || edge-parallel scatter.
// Scatter: packed sd32 load (4B) + rank16 (2B) coalesced; u16 scattered store.
__global__ __launch_bounds__(256)
void fused_mid_kernel(int E, int N, int epb,
                      const unsigned* __restrict__ sd32,
                      const unsigned short* __restrict__ cnt16mat,
                      const unsigned short* __restrict__ rank16,
                      const unsigned* __restrict__ row_start,
                      unsigned short* __restrict__ csr16,
                      const float* __restrict__ x, const _Float16* __restrict__ W1T,
                      const float* __restrict__ as1, const float* __restrict__ ad1,
                      _Float16* __restrict__ h, float* __restrict__ asv,
                      float* __restrict__ adv, int ggrid)
{
  const int bid = blockIdx.x;
  if (bid < ggrid) {
    gemm_mfma_body<256, 4, true>(bid, threadIdx.x, x, W1T, as1, ad1,
                                 h, asv, adv, N);
  } else {
    const int i = (bid - ggrid) * 256 + threadIdx.x;
    const int EE = E + N;
    if (i < EE) {
      const unsigned sd = sd32[i];
      const unsigned d = sd & 0xFFFFu;
      const int b = i / epb;
      unsigned pos = row_start[d] + cnt16mat[(size_t)b * N + d] + rank16[i];
      csr16[pos] = (unsigned short)(sd >> 16);
    }
  }
}

// ---------------------------------------------------------------------------
// FUSED aggregate layer-1 + gemm layer-2 + layer-2 att dots.
__global__ __launch_bounds__(256)
void agg1_gemm2_kernel(const unsigned* __restrict__ row_start,
                       const unsigned* __restrict__ deg,
                       const unsigned short* __restrict__ csr16,
                       const __half* __restrict__ h,
                       const float* __restrict__ a_src,
                       const float* __restrict__ a_dst,
                       const float* __restrict__ bias,
                       const _Float16* __restrict__ W2T,
                       const float* __restrict__ as2, const float* __restrict__ ad2,
                       _Float16* __restrict__ h2,
                       float* __restrict__ asv2, float* __restrict__ adv2, int N)
{
  __shared__ _Float16 actS[16][136];
  __shared__ float sdots[2][16];

  const int lane = threadIdx.x & 63;
  const int wid  = threadIdx.x >> 6;
  const int l5   = lane & 15;
  const int nl   = wid * 4 + (lane >> 4);
  const int nb   = blockIdx.x * 16;
  const int n    = nb + nl;
  const int nn   = min(n, N - 1);
  const int hd   = l5 >> 2;

  // ---------------- phase 1: aggregate (H=4) ----------------
  const float adn = a_dst[(size_t)nn * 4 + hd];
  const unsigned beg = row_start[nn];
  const unsigned cnt = deg[nn];
  unsigned cmax = cnt;
  cmax = max(cmax, (unsigned)__shfl_xor((int)cmax, 16));
  cmax = max(cmax, (unsigned)__shfl_xor((int)cmax, 32));

  const float4* __restrict__ h4 = (const float4*)h;

  float Z = 0.f;
  float acc[8];
#pragma unroll
  for (int j = 0; j < 8; ++j) acc[j] = 0.f;

  unsigned i = 0;
  for (; i + 2 <= cmax; i += 2) {
    unsigned s0 = csr16[beg + min(i,     cnt - 1)];
    unsigned s1 = csr16[beg + min(i + 1, cnt - 1)];
    float e0 = a_src[(size_t)s0 * 4 + hd] + adn;
    float e1 = a_src[(size_t)s1 * 4 + hd] + adn;
    float4 v0 = h4[(size_t)s0 * 16 + l5];
    float4 v1 = h4[(size_t)s1 * 16 + l5];
    e0 = (e0 >= 0.f) ? e0 : SLOPE_ATT * e0;
    e1 = (e1 >= 0.f) ? e1 : SLOPE_ATT * e1;
    float w0 = (i     < cnt) ? __expf(e0) : 0.f;
    float w1 = (i + 1 < cnt) ? __expf(e1) : 0.f;
    Z += w0 + w1;
    const __half2* p0 = (const __half2*)&v0;
    const __half2* p1 = (const __half2*)&v1;
#pragma unroll
    for (int j = 0; j < 4; ++j) {
      float2 f0 = __half22float2(p0[j]);
      float2 f1 = __half22float2(p1[j]);
      acc[2*j]   += w0 * f0.x + w1 * f1.x;
      acc[2*j+1] += w0 * f0.y + w1 * f1.y;
    }
  }
  if (i < cmax) {
    unsigned s0 = csr16[beg + min(i, cnt - 1)];
    float e0 = a_src[(size_t)s0 * 4 + hd] + adn;
    float4 v0 = h4[(size_t)s0 * 16 + l5];
    e0 = (e0 >= 0.f) ? e0 : SLOPE_ATT * e0;
    float w0 = (i < cnt) ? __expf(e0) : 0.f;
    Z += w0;
    const __half2* p0 = (const __half2*)&v0;
#pragma unroll
    for (int j = 0; j < 4; ++j) {
      float2 f0 = __half22float2(p0[j]);
      acc[2*j]   += w0 * f0.x;
      acc[2*j+1] += w0 * f0.y;
    }
  }

  const float inv = 1.f / (Z + 1e-16f);
  float4 b0 = ((const float4*)bias)[l5 * 2];
  float4 b1 = ((const float4*)bias)[l5 * 2 + 1];
  float o[8];
  o[0] = acc[0] * inv + b0.x;  o[1] = acc[1] * inv + b0.y;
  o[2] = acc[2] * inv + b0.z;  o[3] = acc[3] * inv + b0.w;
  o[4] = acc[4] * inv + b1.x;  o[5] = acc[5] * inv + b1.y;
  o[6] = acc[6] * inv + b1.z;  o[7] = acc[7] * inv + b1.w;
#pragma unroll
  for (int j = 0; j < 8; ++j) o[j] = (o[j] >= 0.f) ? o[j] : SLOPE_ACT * o[j];

  // ---------------- phase 2: stage act1 to LDS ----------------
#pragma unroll
  for (int j = 0; j < 8; ++j) actS[nl][l5 * 8 + j] = (_Float16)o[j];
  if (threadIdx.x < 32) sdots[threadIdx.x >> 4][threadIdx.x & 15] = 0.f;
  __syncthreads();

  // ---------------- phase 3: mini-GEMM h2 = act1 @ W2 ----------------
  const int li = l5;
  const int lk = lane >> 4;
#pragma unroll
  for (int t = 0; t < 2; ++t) {
    const int c0 = wid * 32 + t * 16;
    f32x4 a2 = (f32x4){0.f, 0.f, 0.f, 0.f};
#pragma unroll
    for (int ks = 0; ks < 4; ++ks) {
      hf8 af = *(const hf8*)&actS[li][ks * 32 + lk * 8];
      hf8 bf = *(const hf8*)&W2T[(size_t)(c0 + li) * 128 + ks * 32 + lk * 8];
      a2 = __builtin_amdgcn_mfma_f32_16x16x32_f16(af, bf, a2, 0, 0, 0);
    }
    const float asc = as2[c0 + li];
    const float adc = ad2[c0 + li];
#pragma unroll
    for (int reg = 0; reg < 4; ++reg) {
      const int r = lk * 4 + reg;
      float hv = a2[reg];
      if (nb + r < N) h2[(size_t)(nb + r) * 128 + c0 + li] = (_Float16)hv;
      float sp = hv * asc;
      float dp = hv * adc;
      sp += __shfl_xor(sp, 1); sp += __shfl_xor(sp, 2);
      sp += __shfl_xor(sp, 4); sp += __shfl_xor(sp, 8);
      dp += __shfl_xor(dp, 1); dp += __shfl_xor(dp, 2);
      dp += __shfl_xor(dp, 4); dp += __shfl_xor(dp, 8);
      if (li == 0) {
        atomicAdd(&sdots[0][r], sp);
        atomicAdd(&sdots[1][r], dp);
      }
    }
  }
  __syncthreads();
  if (threadIdx.x < 16) {
    const int r = threadIdx.x;
    if (nb + r < N) {
      asv2[nb + r] = sdots[0][r];
      adv2[nb + r] = sdots[1][r];
    }
  }
}

// ---------------------------------------------------------------------------
// Aggregation v2 (H=1, fp32 out) for layer 2 -> d_out.
__global__ __launch_bounds__(256)
void aggregate2_kernel(const unsigned* __restrict__ row_start,
                       const unsigned* __restrict__ deg,
                       const unsigned short* __restrict__ csr16,
                       const __half* __restrict__ h,
                       const float* __restrict__ a_src,
                       const float* __restrict__ a_dst,
                       const float* __restrict__ bias,
                       float* __restrict__ out, int N)
{
  const int lane = threadIdx.x & 63;
  const int wid  = threadIdx.x >> 6;
  const int l5   = lane & 15;
  const int n    = blockIdx.x * 16 + wid * 4 + (lane >> 4);
  const int nn   = min(n, N - 1);

  const float adn = a_dst[nn];
  const unsigned beg = row_start[nn];
  const unsigned cnt = deg[nn];
  unsigned cmax = cnt;
  cmax = max(cmax, (unsigned)__shfl_xor((int)cmax, 16));
  cmax = max(cmax, (unsigned)__shfl_xor((int)cmax, 32));

  const float4* __restrict__ h4 = (const float4*)h;

  float Z = 0.f;
  float acc[8];
#pragma unroll
  for (int j = 0; j < 8; ++j) acc[j] = 0.f;

  unsigned i = 0;
  for (; i + 2 <= cmax; i += 2) {
    unsigned s0 = csr16[beg + min(i,     cnt - 1)];
    unsigned s1 = csr16[beg + min(i + 1, cnt - 1)];
    float e0 = a_src[s0] + adn;
    float e1 = a_src[s1] + adn;
    float4 v0 = h4[(size_t)s0 * 16 + l5];
    float4 v1 = h4[(size_t)s1 * 16 + l5];
    e0 = (e0 >= 0.f) ? e0 : SLOPE_ATT * e0;
    e1 = (e1 >= 0.f) ? e1 : SLOPE_ATT * e1;
    float w0 = (i     < cnt) ? __expf(e0) : 0.f;
    float w1 = (i + 1 < cnt) ? __expf(e1) : 0.f;
    Z += w0 + w1;
    const __half2* p0 = (const __half2*)&v0;
    const __half2* p1 = (const __half2*)&v1;
#pragma unroll
    for (int j = 0; j < 4; ++j) {
      float2 f0 = __half22float2(p0[j]);
      float2 f1 = __half22float2(p1[j]);
      acc[2*j]   += w0 * f0.x + w1 * f1.x;
      acc[2*j+1] += w0 * f0.y + w1 * f1.y;
    }
  }
  if (i < cmax) {
    unsigned s0 = csr16[beg + min(i, cnt - 1)];
    float e0 = a_src[s0] + adn;
    float4 v0 = h4[(size_t)s0 * 16 + l5];
    e0 = (e0 >= 0.f) ? e0 : SLOPE_ATT * e0;
    float w0 = (i < cnt) ? __expf(e0) : 0.f;
    Z += w0;
    const __half2* p0 = (const __half2*)&v0;
#pragma unroll
    for (int j = 0; j < 4; ++j) {
      float2 f0 = __half22float2(p0[j]);
      acc[2*j]   += w0 * f0.x;
      acc[2*j+1] += w0 * f0.y;
    }
  }

  const float inv = 1.f / (Z + 1e-16f);
  float4 b0 = ((const float4*)bias)[l5 * 2];
  float4 b1 = ((const float4*)bias)[l5 * 2 + 1];
  float o[8];
  o[0] = acc[0] * inv + b0.x;  o[1] = acc[1] * inv + b0.y;
  o[2] = acc[2] * inv + b0.z;  o[3] = acc[3] * inv + b0.w;
  o[4] = acc[4] * inv + b1.x;  o[5] = acc[5] * inv + b1.y;
  o[6] = acc[6] * inv + b1.z;  o[7] = acc[7] * inv + b1.w;
#pragma unroll
  for (int j = 0; j < 8; ++j) o[j] = (o[j] >= 0.f) ? o[j] : SLOPE_ACT * o[j];

  if (n < N) {
    ((float4*)out)[(size_t)n * 32 + l5 * 2]     = make_float4(o[0], o[1], o[2], o[3]);
    ((float4*)out)[(size_t)n * 32 + l5 * 2 + 1] = make_float4(o[4], o[5], o[6], o[7]);
  }
}

// ---------------------------------------------------------------------------
extern "C" void kernel_launch(void* const* d_in, const int* in_sizes, int n_in,
                              void* d_out, int out_size, void* d_ws, size_t ws_size,
                              hipStream_t stream)
{
  const float* x   = (const float*)d_in[0];
  const int*   ei  = (const int*)d_in[1];
  const float* W1  = (const float*)d_in[2];
  const float* as1 = (const float*)d_in[3];
  const float* ad1 = (const float*)d_in[4];
  const float* b1  = (const float*)d_in[5];
  const float* W2  = (const float*)d_in[6];
  const float* as2 = (const float*)d_in[7];
  const float* ad2 = (const float*)d_in[8];
  const float* b2  = (const float*)d_in[9];
  float* out = (float*)d_out;

  const int N  = in_sizes[0] / 256;
  const int E  = in_sizes[1] / 2;
  const int EE = E + N;
  const int NCH  = (N + CHUNK - 1) / CHUNK;    // dst chunks
  const int nblk = (N + 511) / 512;            // colscan/rowstart blocks (<=256)
  const int NSC  = NB_CSR * NCH;               // count blocks
  const int epb  = (EE + NB_CSR - 1) / NB_CSR; // edges per count range
  const int pgrid = (EE + 255) / 256;          // packing blocks

  float* ws = (float*)d_ws;
  size_t o = 0;
  _Float16* h    = (_Float16*)(ws + o); o += (size_t)N * 64;   // layer-1 h [N][128] fp16
  _Float16* h2   = (_Float16*)(ws + o); o += (size_t)N * 64;   // layer-2 h [N][128] fp16
  float* asv  = ws + o; o += (size_t)N * 4;                    // layer-1 dots (H=4)
  float* adv  = ws + o; o += (size_t)N * 4;
  float* asv2 = ws + o; o += (size_t)N;                        // layer-2 dots (H=1)
  float* adv2 = ws + o; o += (size_t)N;
  _Float16* W1T = (_Float16*)(ws + o); o += 128 * 256 / 2;     // [128][256] fp16
  _Float16* W2T = (_Float16*)(ws + o); o += 128 * 128 / 2;     // [128][128] fp16
  unsigned* deg       = (unsigned*)(ws + o); o += (size_t)N;
  unsigned* row_start = (unsigned*)(ws + o); o += (size_t)N;
  unsigned* bsum      = (unsigned*)(ws + o); o += 256;
  unsigned* sd32      = (unsigned*)(ws + o); o += (size_t)EE;                        // 3.4 MB
  unsigned short* csr16    = (unsigned short*)(ws + o); o += (size_t)(EE + 1) / 2;   // 1.7 MB
  unsigned short* cnt16mat = (unsigned short*)(ws + o); o += (size_t)NB_CSR * N / 2; // 12.8 MB
  unsigned short* rank16   = (unsigned short*)(ws + o); o += (size_t)(EE + 1) / 2;   // 1.7 MB

  const int ngrid = (N + 15) / 16;
  const int ggrid = (N + 127) / 128;
  const int sgrid = (EE + 255) / 256;

  // 1) count+rank || convW1 || convW2 || sd32 packing
  fused_pre_kernel<<<NSC + 192 + pgrid, 256, 0, stream>>>(
      ei, E, N, cnt16mat, rank16, sd32, W1, W1T, W2, W2T, NSC);
  // 2) column scan (packed u16 x2) + block sums
  colscan_kernel<<<nblk, 256, 0, stream>>>(cnt16mat, deg, bsum, N);
  // 3) row starts (inline bsum scan)
  rowstart_kernel<<<nblk, 256, 0, stream>>>(deg, bsum, row_start, N, nblk);
  // 4) gemm layer-1 || edge-parallel scatter (u16 stores)
  fused_mid_kernel<<<ggrid + sgrid, 256, 0, stream>>>(
      E, N, epb, sd32, cnt16mat, rank16, row_start, csr16,
      x, W1T, as1, ad1, h, asv, adv, ggrid);
  // 5) aggregate layer-1 + gemm layer-2 + layer-2 dots (fused)
  agg1_gemm2_kernel<<<ngrid, 256, 0, stream>>>(
      row_start, deg, csr16, (const __half*)h, asv, adv, b1,
      W2T, as2, ad2, h2, asv2, adv2, N);
  // 6) aggregate layer-2 -> out (fp32)
  aggregate2_kernel<<<ngrid, 256, 0, stream>>>(
      row_start, deg, csr16, (const __half*)h2, asv2, adv2, b2, out, N);
}

// Round 16
// 143.968 us; speedup vs baseline: 1.5188x; 1.1721x over previous
//
#include <hip/hip_runtime.h>
#include <hip/hip_fp16.h>

#define SLOPE_ATT 0.2f
#define SLOPE_ACT 0.01f

#define SB 256        // edge-range blocks for count/scatter
#define NBUKMAX 512   // max coarse buckets (dst>>7, N<=65536)

typedef _Float16 hf8 __attribute__((ext_vector_type(8)));
typedef float f32x4 __attribute__((ext_vector_type(4)));

// ---------------------------------------------------------------------------
// MFMA fp16 GEMM body: h[M][128] = A[M][K] @ B[K][128], BT[128][K] fp16.
template<int K, int H, bool A_FP32>
__device__ __forceinline__
void gemm_mfma_body(int gbid, int tid,
                    const void* __restrict__ Av, const _Float16* __restrict__ BT,
                    const float* __restrict__ att_s, const float* __restrict__ att_d,
                    _Float16* __restrict__ hout, float* __restrict__ a_src,
                    float* __restrict__ a_dst, int M)
{
  const int lane = tid & 63;
  const int wid  = tid >> 6;
  const int li   = lane & 15;
  const int lk   = lane >> 4;
  const int rowbase = gbid * 128 + wid * 32;

  const float*    Af = (const float*)Av;
  const _Float16* Ah = (const _Float16*)Av;

  f32x4 acc[2][8];
#pragma unroll
  for (int i = 0; i < 2; ++i)
#pragma unroll
    for (int j = 0; j < 8; ++j) acc[i][j] = (f32x4){0.f, 0.f, 0.f, 0.f};

  const int r0 = min(rowbase + li,      M - 1);
  const int r1 = min(rowbase + 16 + li, M - 1);

#pragma unroll
  for (int ks = 0; ks < K / 32; ++ks) {
    const int kb = ks * 32 + lk * 8;
    hf8 a0, a1;
    if constexpr (A_FP32) {
      const float* p0 = &Af[(size_t)r0 * K + kb];
      const float* p1 = &Af[(size_t)r1 * K + kb];
      float4 x0a = *(const float4*)p0, x0b = *(const float4*)(p0 + 4);
      float4 x1a = *(const float4*)p1, x1b = *(const float4*)(p1 + 4);
      a0[0]=(_Float16)x0a.x; a0[1]=(_Float16)x0a.y; a0[2]=(_Float16)x0a.z; a0[3]=(_Float16)x0a.w;
      a0[4]=(_Float16)x0b.x; a0[5]=(_Float16)x0b.y; a0[6]=(_Float16)x0b.z; a0[7]=(_Float16)x0b.w;
      a1[0]=(_Float16)x1a.x; a1[1]=(_Float16)x1a.y; a1[2]=(_Float16)x1a.z; a1[3]=(_Float16)x1a.w;
      a1[4]=(_Float16)x1b.x; a1[5]=(_Float16)x1b.y; a1[6]=(_Float16)x1b.z; a1[7]=(_Float16)x1b.w;
    } else {
      a0 = *(const hf8*)&Ah[(size_t)r0 * K + kb];
      a1 = *(const hf8*)&Ah[(size_t)r1 * K + kb];
    }
#pragma unroll
    for (int cf = 0; cf < 8; ++cf) {
      hf8 b = *(const hf8*)&BT[(size_t)(cf * 16 + li) * K + kb];
      acc[0][cf] = __builtin_amdgcn_mfma_f32_16x16x32_f16(a0, b, acc[0][cf], 0, 0, 0);
      acc[1][cf] = __builtin_amdgcn_mfma_f32_16x16x32_f16(a1, b, acc[1][cf], 0, 0, 0);
    }
  }

  float sA[8], dA[8];
#pragma unroll
  for (int cf = 0; cf < 8; ++cf) {
    sA[cf] = att_s[cf * 16 + li];
    dA[cf] = att_d[cf * 16 + li];
  }

  const bool full = (rowbase + 32) <= M;
#pragma unroll
  for (int rf = 0; rf < 2; ++rf) {
    const int rb = rowbase + rf * 16 + lk * 4;
#pragma unroll
    for (int reg = 0; reg < 4; ++reg) {
      const int r = rb + reg;
      if (full || r < M) {
#pragma unroll
        for (int cf = 0; cf < 8; ++cf)
          hout[(size_t)r * 128 + cf * 16 + li] = (_Float16)acc[rf][cf][reg];
      }
    }
    if constexpr (H == 4) {
#pragma unroll
      for (int hh = 0; hh < 4; ++hh) {
#pragma unroll
        for (int reg = 0; reg < 4; ++reg) {
          float sp = acc[rf][2*hh][reg] * sA[2*hh] + acc[rf][2*hh+1][reg] * sA[2*hh+1];
          float dp = acc[rf][2*hh][reg] * dA[2*hh] + acc[rf][2*hh+1][reg] * dA[2*hh+1];
          sp += __shfl_xor(sp, 1); sp += __shfl_xor(sp, 2);
          sp += __shfl_xor(sp, 4); sp += __shfl_xor(sp, 8);
          dp += __shfl_xor(dp, 1); dp += __shfl_xor(dp, 2);
          dp += __shfl_xor(dp, 4); dp += __shfl_xor(dp, 8);
          const int r = rb + reg;
          if (li == 0 && r < M) {
            a_src[(size_t)r * 4 + hh] = sp;
            a_dst[(size_t)r * 4 + hh] = dp;
          }
        }
      }
    } else {
#pragma unroll
      for (int reg = 0; reg < 4; ++reg) {
        float sp = 0.f, dp = 0.f;
#pragma unroll
        for (int cf = 0; cf < 8; ++cf) {
          sp += acc[rf][cf][reg] * sA[cf];
          dp += acc[rf][cf][reg] * dA[cf];
        }
        sp += __shfl_xor(sp, 1); sp += __shfl_xor(sp, 2);
        sp += __shfl_xor(sp, 4); sp += __shfl_xor(sp, 8);
        dp += __shfl_xor(dp, 1); dp += __shfl_xor(dp, 2);
        dp += __shfl_xor(dp, 4); dp += __shfl_xor(dp, 8);
        const int r = rb + reg;
        if (li == 0 && r < M) { a_src[r] = sp; a_dst[r] = dp; }
      }
    }
  }
}

// ---------------------------------------------------------------------------
// Dispatch 1: coarse bucket count || convW1 || convW2 || sd32 pack.
__global__ __launch_bounds__(256)
void pre_kernel(const int* __restrict__ ei, int E, int N, int nbuk, int epb1,
                unsigned* __restrict__ cntA, unsigned* __restrict__ sd32,
                const float* __restrict__ W1, _Float16* __restrict__ W1T,
                const float* __restrict__ W2, _Float16* __restrict__ W2T)
{
  __shared__ unsigned hist[NBUKMAX];
  const int bid = blockIdx.x;
  const int tid = threadIdx.x;
  if (bid < SB) {
    for (int j = tid; j < NBUKMAX; j += 256) hist[j] = 0;
    __syncthreads();
    const int EE = E + N;
    const int lo = bid * epb1, hi = min(lo + epb1, EE);
    for (int i = lo + tid; i < hi; i += 256) {
      int d = (i < E) ? ei[E + i] : (i - E);
      atomicAdd(&hist[d >> 7], 1u);
    }
    __syncthreads();
    for (int j = tid; j < nbuk; j += 256)
      cntA[(size_t)bid * NBUKMAX + j] = hist[j];
  } else if (bid < SB + 128) {          // W1: 256x128
    int idx = (bid - SB) * 256 + tid;
    int k = idx >> 7, c = idx & 127;
    W1T[(size_t)c * 256 + k] = (_Float16)W1[idx];
  } else if (bid < SB + 192) {          // W2: 128x128
    int idx = (bid - SB - 128) * 256 + tid;
    int k = idx >> 7, c = idx & 127;
    W2T[(size_t)c * 128 + k] = (_Float16)W2[idx];
  } else {                              // sd32 pack
    const int i = (bid - SB - 192) * 256 + tid;
    const int EE = E + N;
    if (i < EE) {
      unsigned s, d;
      if (i < E) { s = (unsigned)ei[i]; d = (unsigned)ei[E + i]; }
      else       { s = d = (unsigned)(i - E); }
      sd32[i] = (s << 16) | d;
    }
  }
}

// Dispatch 2: per-bucket column scan of cntA -> blkoff (exclusive), buktotal.
__global__ __launch_bounds__(256)
void bukoff_kernel(const unsigned* __restrict__ cntA, unsigned* __restrict__ blkoff,
                   unsigned* __restrict__ buktotal)
{
  __shared__ unsigned s[256];
  const int j = blockIdx.x;
  const int t = threadIdx.x;
  unsigned v0 = cntA[(size_t)t * NBUKMAX + j];
  s[t] = v0;
  __syncthreads();
  for (int off = 1; off < 256; off <<= 1) {
    unsigned v = (t >= off) ? s[t - off] : 0u;
    __syncthreads();
    s[t] += v;
    __syncthreads();
  }
  blkoff[(size_t)t * NBUKMAX + j] = s[t] - v0;
  if (t == 255) buktotal[j] = s[255];
}

// Inline exclusive scan of buktotal[0..nbuk) -> bs[0..nbuk) (512 via 256 thr).
__device__ __forceinline__
void bukstart_scan(const unsigned* __restrict__ buktotal, int nbuk,
                   unsigned* bt, unsigned* ps, unsigned* bs, int tid)
{
  for (int j = tid; j < NBUKMAX; j += 256) bt[j] = (j < nbuk) ? buktotal[j] : 0u;
  __syncthreads();
  unsigned pair = bt[2 * tid] + bt[2 * tid + 1];
  ps[tid] = pair;
  __syncthreads();
  for (int off = 1; off < 256; off <<= 1) {
    unsigned v = (tid >= off) ? ps[tid - off] : 0u;
    __syncthreads();
    ps[tid] += v;
    __syncthreads();
  }
  unsigned e0 = ps[tid] - pair;
  bs[2 * tid]     = e0;
  bs[2 * tid + 1] = e0 + bt[2 * tid];
  __syncthreads();
}

// Dispatch 3: gemm layer-1 || bucket scatter (edges -> ebuk grouped by bucket).
__global__ __launch_bounds__(256)
void gemm1_scatter_kernel(int E, int N, int nbuk, int epb1,
                          const unsigned* __restrict__ sd32,
                          const unsigned* __restrict__ blkoff,
                          const unsigned* __restrict__ buktotal,
                          unsigned* __restrict__ ebuk,
                          const float* __restrict__ x, const _Float16* __restrict__ W1T,
                          const float* __restrict__ as1, const float* __restrict__ ad1,
                          _Float16* __restrict__ h, float* __restrict__ asv,
                          float* __restrict__ adv, int ggrid)
{
  __shared__ unsigned bt[NBUKMAX], bs[NBUKMAX], cur[NBUKMAX];
  __shared__ unsigned ps[256];
  const int bid = blockIdx.x;
  const int tid = threadIdx.x;
  if (bid < ggrid) {
    gemm_mfma_body<256, 4, true>(bid, tid, x, W1T, as1, ad1, h, asv, adv, N);
  } else {
    const int sb = bid - ggrid;
    bukstart_scan(buktotal, nbuk, bt, ps, bs, tid);
    for (int j = tid; j < nbuk; j += 256)
      cur[j] = bs[j] + blkoff[(size_t)sb * NBUKMAX + j];
    __syncthreads();
    const int EE = E + N;
    const int lo = sb * epb1, hi = min(lo + epb1, EE);
    for (int i = lo + tid; i < hi; i += 256) {
      unsigned sd = sd32[i];
      unsigned buk = (sd & 0xFFFFu) >> 7;
      unsigned slot = atomicAdd(&cur[buk], 1u);
      ebuk[slot] = sd;
    }
  }
}

// Dispatch 4: per-bucket CSR build: deg + row_start (coalesced) + csr16
// (rank scatter confined to this bucket's ~4KB region; single block).
__global__ __launch_bounds__(256)
void csr_build_kernel(int N, int nbuk,
                      const unsigned* __restrict__ buktotal,
                      const unsigned* __restrict__ ebuk,
                      unsigned* __restrict__ deg, unsigned* __restrict__ row_start,
                      unsigned short* __restrict__ csr16)
{
  __shared__ unsigned bt[NBUKMAX], bs[NBUKMAX];
  __shared__ unsigned ps[256];
  __shared__ unsigned hist[128], hs[128], cur2[128];
  const int j = blockIdx.x;
  const int tid = threadIdx.x;

  bukstart_scan(buktotal, nbuk, bt, ps, bs, tid);
  const unsigned estart = bs[j];
  const unsigned ecount = bt[j];
  const int n0 = j * 128;

  if (tid < 128) hist[tid] = 0;
  __syncthreads();
  for (unsigned i = estart + tid; i < estart + ecount; i += 256)
    atomicAdd(&hist[ebuk[i] & 127u], 1u);
  __syncthreads();
  unsigned hv = (tid < 128) ? hist[tid] : 0u;
  if (tid < 128) hs[tid] = hv;
  __syncthreads();
  for (int off = 1; off < 128; off <<= 1) {
    unsigned v = 0;
    if (tid < 128 && tid >= off) v = hs[tid - off];
    __syncthreads();
    if (tid < 128) hs[tid] += v;
    __syncthreads();
  }
  if (tid < 128) {
    unsigned excl = hs[tid] - hv;
    cur2[tid] = estart + excl;
    if (n0 + tid < N) {
      deg[n0 + tid] = hv;
      row_start[n0 + tid] = estart + excl;
    }
  }
  __syncthreads();
  for (unsigned i = estart + tid; i < estart + ecount; i += 256) {
    unsigned sd = ebuk[i];
    unsigned slot = atomicAdd(&cur2[sd & 127u], 1u);
    csr16[slot] = (unsigned short)(sd >> 16);
  }
}

// ---------------------------------------------------------------------------
// Dispatch 5: FUSED aggregate layer-1 + gemm layer-2 + layer-2 att dots.
__global__ __launch_bounds__(256)
void agg1_gemm2_kernel(const unsigned* __restrict__ row_start,
                       const unsigned* __restrict__ deg,
                       const unsigned short* __restrict__ csr16,
                       const __half* __restrict__ h,
                       const float* __restrict__ a_src,
                       const float* __restrict__ a_dst,
                       const float* __restrict__ bias,
                       const _Float16* __restrict__ W2T,
                       const float* __restrict__ as2, const float* __restrict__ ad2,
                       _Float16* __restrict__ h2,
                       float* __restrict__ asv2, float* __restrict__ adv2, int N)
{
  __shared__ _Float16 actS[16][132];   // stride 264B = 66 words: 2-way banks max
  __shared__ float sdots[2][16];

  const int lane = threadIdx.x & 63;
  const int wid  = threadIdx.x >> 6;
  const int l5   = lane & 15;
  const int nl   = wid * 4 + (lane >> 4);
  const int nb   = blockIdx.x * 16;
  const int n    = nb + nl;
  const int nn   = min(n, N - 1);
  const int hd   = l5 >> 2;

  // phase 1: aggregate (H=4)
  const float adn = a_dst[(size_t)nn * 4 + hd];
  const unsigned beg = row_start[nn];
  const unsigned cnt = deg[nn];
  unsigned cmax = cnt;
  cmax = max(cmax, (unsigned)__shfl_xor((int)cmax, 16));
  cmax = max(cmax, (unsigned)__shfl_xor((int)cmax, 32));

  const float4* __restrict__ h4 = (const float4*)h;

  float Z = 0.f;
  float acc[8];
#pragma unroll
  for (int j = 0; j < 8; ++j) acc[j] = 0.f;

  unsigned i = 0;
  for (; i + 2 <= cmax; i += 2) {
    unsigned s0 = csr16[beg + min(i,     cnt - 1)];
    unsigned s1 = csr16[beg + min(i + 1, cnt - 1)];
    float e0 = a_src[(size_t)s0 * 4 + hd] + adn;
    float e1 = a_src[(size_t)s1 * 4 + hd] + adn;
    float4 v0 = h4[(size_t)s0 * 16 + l5];
    float4 v1 = h4[(size_t)s1 * 16 + l5];
    e0 = (e0 >= 0.f) ? e0 : SLOPE_ATT * e0;
    e1 = (e1 >= 0.f) ? e1 : SLOPE_ATT * e1;
    float w0 = (i     < cnt) ? __expf(e0) : 0.f;
    float w1 = (i + 1 < cnt) ? __expf(e1) : 0.f;
    Z += w0 + w1;
    const __half2* p0 = (const __half2*)&v0;
    const __half2* p1 = (const __half2*)&v1;
#pragma unroll
    for (int j = 0; j < 4; ++j) {
      float2 f0 = __half22float2(p0[j]);
      float2 f1 = __half22float2(p1[j]);
      acc[2*j]   += w0 * f0.x + w1 * f1.x;
      acc[2*j+1] += w0 * f0.y + w1 * f1.y;
    }
  }
  if (i < cmax) {
    unsigned s0 = csr16[beg + min(i, cnt - 1)];
    float e0 = a_src[(size_t)s0 * 4 + hd] + adn;
    float4 v0 = h4[(size_t)s0 * 16 + l5];
    e0 = (e0 >= 0.f) ? e0 : SLOPE_ATT * e0;
    float w0 = (i < cnt) ? __expf(e0) : 0.f;
    Z += w0;
    const __half2* p0 = (const __half2*)&v0;
#pragma unroll
    for (int j = 0; j < 4; ++j) {
      float2 f0 = __half22float2(p0[j]);
      acc[2*j]   += w0 * f0.x;
      acc[2*j+1] += w0 * f0.y;
    }
  }

  const float inv = 1.f / (Z + 1e-16f);
  float4 b0 = ((const float4*)bias)[l5 * 2];
  float4 b1 = ((const float4*)bias)[l5 * 2 + 1];
  float o[8];
  o[0] = acc[0] * inv + b0.x;  o[1] = acc[1] * inv + b0.y;
  o[2] = acc[2] * inv + b0.z;  o[3] = acc[3] * inv + b0.w;
  o[4] = acc[4] * inv + b1.x;  o[5] = acc[5] * inv + b1.y;
  o[6] = acc[6] * inv + b1.z;  o[7] = acc[7] * inv + b1.w;
#pragma unroll
  for (int j = 0; j < 8; ++j) o[j] = (o[j] >= 0.f) ? o[j] : SLOPE_ACT * o[j];

  // phase 2: stage act1
#pragma unroll
  for (int j = 0; j < 8; ++j) actS[nl][l5 * 8 + j] = (_Float16)o[j];
  if (threadIdx.x < 32) sdots[threadIdx.x >> 4][threadIdx.x & 15] = 0.f;
  __syncthreads();

  // phase 3: mini-GEMM h2 = act1 @ W2 + H=1 dots
  const int li = l5;
  const int lk = lane >> 4;
#pragma unroll
  for (int t = 0; t < 2; ++t) {
    const int c0 = wid * 32 + t * 16;
    f32x4 a2 = (f32x4){0.f, 0.f, 0.f, 0.f};
#pragma unroll
    for (int ks = 0; ks < 4; ++ks) {
      hf8 af = *(const hf8*)&actS[li][ks * 32 + lk * 8];
      hf8 bf = *(const hf8*)&W2T[(size_t)(c0 + li) * 128 + ks * 32 + lk * 8];
      a2 = __builtin_amdgcn_mfma_f32_16x16x32_f16(af, bf, a2, 0, 0, 0);
    }
    const float asc = as2[c0 + li];
    const float adc = ad2[c0 + li];
#pragma unroll
    for (int reg = 0; reg < 4; ++reg) {
      const int r = lk * 4 + reg;
      float hv = a2[reg];
      if (nb + r < N) h2[(size_t)(nb + r) * 128 + c0 + li] = (_Float16)hv;
      float sp = hv * asc;
      float dp = hv * adc;
      sp += __shfl_xor(sp, 1); sp += __shfl_xor(sp, 2);
      sp += __shfl_xor(sp, 4); sp += __shfl_xor(sp, 8);
      dp += __shfl_xor(dp, 1); dp += __shfl_xor(dp, 2);
      dp += __shfl_xor(dp, 4); dp += __shfl_xor(dp, 8);
      if (li == 0) {
        atomicAdd(&sdots[0][r], sp);
        atomicAdd(&sdots[1][r], dp);
      }
    }
  }
  __syncthreads();
  if (threadIdx.x < 16) {
    const int r = threadIdx.x;
    if (nb + r < N) {
      asv2[nb + r] = sdots[0][r];
      adv2[nb + r] = sdots[1][r];
    }
  }
}

// ---------------------------------------------------------------------------
// Dispatch 6: aggregate layer-2 (H=1, fp32 out) -> d_out.
__global__ __launch_bounds__(256)
void aggregate2_kernel(const unsigned* __restrict__ row_start,
                       const unsigned* __restrict__ deg,
                       const unsigned short* __restrict__ csr16,
                       const __half* __restrict__ h,
                       const float* __restrict__ a_src,
                       const float* __restrict__ a_dst,
                       const float* __restrict__ bias,
                       float* __restrict__ out, int N)
{
  const int lane = threadIdx.x & 63;
  const int wid  = threadIdx.x >> 6;
  const int l5   = lane & 15;
  const int n    = blockIdx.x * 16 + wid * 4 + (lane >> 4);
  const int nn   = min(n, N - 1);

  const float adn = a_dst[nn];
  const unsigned beg = row_start[nn];
  const unsigned cnt = deg[nn];
  unsigned cmax = cnt;
  cmax = max(cmax, (unsigned)__shfl_xor((int)cmax, 16));
  cmax = max(cmax, (unsigned)__shfl_xor((int)cmax, 32));

  const float4* __restrict__ h4 = (const float4*)h;

  float Z = 0.f;
  float acc[8];
#pragma unroll
  for (int j = 0; j < 8; ++j) acc[j] = 0.f;

  unsigned i = 0;
  for (; i + 2 <= cmax; i += 2) {
    unsigned s0 = csr16[beg + min(i,     cnt - 1)];
    unsigned s1 = csr16[beg + min(i + 1, cnt - 1)];
    float e0 = a_src[s0] + adn;
    float e1 = a_src[s1] + adn;
    float4 v0 = h4[(size_t)s0 * 16 + l5];
    float4 v1 = h4[(size_t)s1 * 16 + l5];
    e0 = (e0 >= 0.f) ? e0 : SLOPE_ATT * e0;
    e1 = (e1 >= 0.f) ? e1 : SLOPE_ATT * e1;
    float w0 = (i     < cnt) ? __expf(e0) : 0.f;
    float w1 = (i + 1 < cnt) ? __expf(e1) : 0.f;
    Z += w0 + w1;
    const __half2* p0 = (const __half2*)&v0;
    const __half2* p1 = (const __half2*)&v1;
#pragma unroll
    for (int j = 0; j < 4; ++j) {
      float2 f0 = __half22float2(p0[j]);
      float2 f1 = __half22float2(p1[j]);
      acc[2*j]   += w0 * f0.x + w1 * f1.x;
      acc[2*j+1] += w0 * f0.y + w1 * f1.y;
    }
  }
  if (i < cmax) {
    unsigned s0 = csr16[beg + min(i, cnt - 1)];
    float e0 = a_src[s0] + adn;
    float4 v0 = h4[(size_t)s0 * 16 + l5];
    e0 = (e0 >= 0.f) ? e0 : SLOPE_ATT * e0;
    float w0 = (i < cnt) ? __expf(e0) : 0.f;
    Z += w0;
    const __half2* p0 = (const __half2*)&v0;
#pragma unroll
    for (int j = 0; j < 4; ++j) {
      float2 f0 = __half22float2(p0[j]);
      acc[2*j]   += w0 * f0.x;
      acc[2*j+1] += w0 * f0.y;
    }
  }

  const float inv = 1.f / (Z + 1e-16f);
  float4 b0 = ((const float4*)bias)[l5 * 2];
  float4 b1 = ((const float4*)bias)[l5 * 2 + 1];
  float o[8];
  o[0] = acc[0] * inv + b0.x;  o[1] = acc[1] * inv + b0.y;
  o[2] = acc[2] * inv + b0.z;  o[3] = acc[3] * inv + b0.w;
  o[4] = acc[4] * inv + b1.x;  o[5] = acc[5] * inv + b1.y;
  o[6] = acc[6] * inv + b1.z;  o[7] = acc[7] * inv + b1.w;
#pragma unroll
  for (int j = 0; j < 8; ++j) o[j] = (o[j] >= 0.f) ? o[j] : SLOPE_ACT * o[j];

  if (n < N) {
    ((float4*)out)[(size_t)n * 32 + l5 * 2]     = make_float4(o[0], o[1], o[2], o[3]);
    ((float4*)out)[(size_t)n * 32 + l5 * 2 + 1] = make_float4(o[4], o[5], o[6], o[7]);
  }
}

// ---------------------------------------------------------------------------
extern "C" void kernel_launch(void* const* d_in, const int* in_sizes, int n_in,
                              void* d_out, int out_size, void* d_ws, size_t ws_size,
                              hipStream_t stream)
{
  const float* x   = (const float*)d_in[0];
  const int*   ei  = (const int*)d_in[1];
  const float* W1  = (const float*)d_in[2];
  const float* as1 = (const float*)d_in[3];
  const float* ad1 = (const float*)d_in[4];
  const float* b1  = (const float*)d_in[5];
  const float* W2  = (const float*)d_in[6];
  const float* as2 = (const float*)d_in[7];
  const float* ad2 = (const float*)d_in[8];
  const float* b2  = (const float*)d_in[9];
  float* out = (float*)d_out;

  const int N  = in_sizes[0] / 256;
  const int E  = in_sizes[1] / 2;
  const int EE = E + N;
  const int nbuk = (N + 127) / 128;            // <= 512 for N <= 65536
  const int epb1 = (EE + SB - 1) / SB;         // edges per count/scatter block
  const int pgrid = (EE + 255) / 256;          // packing blocks

  float* ws = (float*)d_ws;
  size_t o = 0;
  _Float16* h    = (_Float16*)(ws + o); o += (size_t)N * 64;   // layer-1 h [N][128] fp16
  _Float16* h2   = (_Float16*)(ws + o); o += (size_t)N * 64;   // layer-2 h [N][128] fp16
  float* asv  = ws + o; o += (size_t)N * 4;                    // layer-1 dots (H=4)
  float* adv  = ws + o; o += (size_t)N * 4;
  float* asv2 = ws + o; o += (size_t)N;                        // layer-2 dots (H=1)
  float* adv2 = ws + o; o += (size_t)N;
  _Float16* W1T = (_Float16*)(ws + o); o += 128 * 256 / 2;     // [128][256] fp16
  _Float16* W2T = (_Float16*)(ws + o); o += 128 * 128 / 2;     // [128][128] fp16
  unsigned* deg       = (unsigned*)(ws + o); o += (size_t)N;
  unsigned* row_start = (unsigned*)(ws + o); o += (size_t)N;
  unsigned* cntA      = (unsigned*)(ws + o); o += (size_t)SB * NBUKMAX;   // 512 KB
  unsigned* blkoff    = (unsigned*)(ws + o); o += (size_t)SB * NBUKMAX;   // 512 KB
  unsigned* buktotal  = (unsigned*)(ws + o); o += NBUKMAX;
  unsigned* sd32      = (unsigned*)(ws + o); o += (size_t)EE;             // 3.4 MB
  unsigned* ebuk      = (unsigned*)(ws + o); o += (size_t)EE;             // 3.4 MB
  unsigned short* csr16 = (unsigned short*)(ws + o); o += (size_t)(EE + 1) / 2; // 1.7 MB

  const int ngrid = (N + 15) / 16;
  const int ggrid = (N + 127) / 128;

  // 1) bucket count || convW1 || convW2 || sd32 pack
  pre_kernel<<<SB + 192 + pgrid, 256, 0, stream>>>(
      ei, E, N, nbuk, epb1, cntA, sd32, W1, W1T, W2, W2T);
  // 2) per-bucket column scan
  bukoff_kernel<<<nbuk, 256, 0, stream>>>(cntA, blkoff, buktotal);
  // 3) gemm layer-1 || bucket scatter
  gemm1_scatter_kernel<<<ggrid + SB, 256, 0, stream>>>(
      E, N, nbuk, epb1, sd32, blkoff, buktotal, ebuk,
      x, W1T, as1, ad1, h, asv, adv, ggrid);
  // 4) per-bucket CSR build (deg + row_start + csr16, all bucket-local)
  csr_build_kernel<<<nbuk, 256, 0, stream>>>(
      N, nbuk, buktotal, ebuk, deg, row_start, csr16);
  // 5) aggregate layer-1 + gemm layer-2 + layer-2 dots (fused)
  agg1_gemm2_kernel<<<ngrid, 256, 0, stream>>>(
      row_start, deg, csr16, (const __half*)h, asv, adv, b1,
      W2T, as2, ad2, h2, asv2, adv2, N);
  // 6) aggregate layer-2 -> out (fp32)
  aggregate2_kernel<<<ngrid, 256, 0, stream>>>(
      row_start, deg, csr16, (const __half*)h2, asv2, adv2, b2, out, N);
}